// Round 2
// baseline (1360.917 us; speedup 1.0000x reference)
//
#include <hip/hip_runtime.h>
#include <hip/hip_bf16.h>
#include <math.h>

// Shapes (fixed by setup_inputs): B=2, N=2048, D=1024, H=16, d=64, n_ctx=1024, P=256
// All fp32. 4 kernels: bias/gate, QKV gemm (+scatter+gate), flash attn, out-proj gemm.
// fp32 exact-semantics anchor (no fp32 MFMA on CDNA4 -> vector-ALU bound ~157 TF).

#define NTOK 2048      // N
#define DMODEL 1024    // D
#define NHEAD 16
#define DHEAD 64
#define NCTX 1024
#define BTOT 4096      // B*N rows

// ---------------------------------------------------------------- bias kernel
__global__ __launch_bounds__(256)
void bias_kernel(const float* __restrict__ ctx_ppr, const float* __restrict__ ctx_delta,
                 const float* __restrict__ ctx_trust,
                 const float* __restrict__ alpha, const float* __restrict__ tscale,
                 const float* __restrict__ Wd1, const float* __restrict__ bd1,
                 const float* __restrict__ Wd2, const float* __restrict__ bd2,
                 float* __restrict__ gate_full, float* __restrict__ col_bias)
{
    const int i = blockIdx.x;   // key index 0..NTOK-1
    const int t = threadIdx.x;  // 0..255
    if (i >= NCTX) {
        if (t == 0) { gate_full[i] = 1.0f; col_bias[i] = 0.0f; }
        return;
    }
    __shared__ float drow[256];
    __shared__ float red[256];
    drow[t] = ctx_delta[i * 256 + t];
    __syncthreads();

    float partial = 0.0f;
    #pragma unroll
    for (int jj = 0; jj < 2; jj++) {
        const int j = t + jj * 256;          // 0..511
        float s = bd1[j];
        const float4* wrow = (const float4*)&Wd1[j * 256];
        const float4* dr   = (const float4*)drow;
        #pragma unroll 8
        for (int p = 0; p < 64; p++) {
            float4 w = wrow[p], dd = dr[p];
            s += w.x * dd.x + w.y * dd.y + w.z * dd.z + w.w * dd.w;
        }
        // exact gelu: 0.5*x*(1+erf(x/sqrt(2)))
        float g = 0.5f * s * (1.0f + erff(s * 0.70710678118654752f));
        partial += g * Wd2[j];
    }
    red[t] = partial;
    __syncthreads();
    for (int off = 128; off > 0; off >>= 1) {
        if (t < off) red[t] += red[t + off];
        __syncthreads();
    }
    if (t == 0) {
        float ppr = fmaxf(ctx_ppr[i], 1e-8f);
        col_bias[i]  = alpha[0] * logf(ppr) + (red[0] + bd2[0]);
        gate_full[i] = 1.0f / (1.0f + __expf(-(tscale[0] * ctx_trust[i])));
    }
}

// ---------------------------------------------------------------- GEMM  C = A @ B^T + bias
// A [M][K] row-major, B [N][K] row-major. Tile 128x128, 256 threads, 8x8/thread, BK=16.
// Register prefetch of tile k+1 hides global latency under the FMA loop.
// EPI=0: C[m*N+n] = acc + bias[n]
// EPI=1: scatter to q/k/v head layout [B,H,N,d]; v gets gate_full[token]
template<int EPI>
__global__ __launch_bounds__(256)
void gemm_bt(const float* __restrict__ A, const float* __restrict__ B,
             const float* __restrict__ bias, float* __restrict__ C,
             float* __restrict__ qw, float* __restrict__ kw, float* __restrict__ vw,
             const float* __restrict__ gate_full, int M, int N, int K)
{
    __shared__ float As[16][132];   // +4 pad: reduces staging-write conflicts to 2-way
    __shared__ float Bs[16][132];
    const int t  = threadIdx.x;
    const int tx = t & 15, ty = t >> 4;
    const int m0 = blockIdx.y * 128, n0 = blockIdx.x * 128;
    const int lr = t >> 2, lc = (t & 3) * 4;

    float acc[8][8] = {};
    float4 pva[2], pvb[2];

    #pragma unroll
    for (int i = 0; i < 2; i++) {
        const int row = lr + i * 64;
        pva[i] = *(const float4*)&A[(m0 + row) * K + lc];
        pvb[i] = *(const float4*)&B[(n0 + row) * K + lc];
    }

    for (int k0 = 0; k0 < K; k0 += 16) {
        __syncthreads();
        #pragma unroll
        for (int i = 0; i < 2; i++) {
            const int row = lr + i * 64;
            As[lc + 0][row] = pva[i].x; As[lc + 1][row] = pva[i].y;
            As[lc + 2][row] = pva[i].z; As[lc + 3][row] = pva[i].w;
            Bs[lc + 0][row] = pvb[i].x; Bs[lc + 1][row] = pvb[i].y;
            Bs[lc + 2][row] = pvb[i].z; Bs[lc + 3][row] = pvb[i].w;
        }
        __syncthreads();
        if (k0 + 16 < K) {
            #pragma unroll
            for (int i = 0; i < 2; i++) {
                const int row = lr + i * 64;
                pva[i] = *(const float4*)&A[(m0 + row) * K + k0 + 16 + lc];
                pvb[i] = *(const float4*)&B[(n0 + row) * K + k0 + 16 + lc];
            }
        }
        #pragma unroll
        for (int k = 0; k < 16; k++) {
            float a[8], b[8];
            *(float4*)&a[0] = *(const float4*)&As[k][ty * 8];
            *(float4*)&a[4] = *(const float4*)&As[k][ty * 8 + 4];
            *(float4*)&b[0] = *(const float4*)&Bs[k][tx * 8];
            *(float4*)&b[4] = *(const float4*)&Bs[k][tx * 8 + 4];
            #pragma unroll
            for (int i = 0; i < 8; i++)
                #pragma unroll
                for (int j = 0; j < 8; j++)
                    acc[i][j] = fmaf(a[i], b[j], acc[i][j]);
        }
    }

    if (EPI == 0) {
        #pragma unroll
        for (int i = 0; i < 8; i++) {
            const int m = m0 + ty * 8 + i;
            #pragma unroll
            for (int j4 = 0; j4 < 8; j4 += 4) {
                const int n = n0 + tx * 8 + j4;
                float4 o;
                o.x = acc[i][j4 + 0] + bias[n + 0];
                o.y = acc[i][j4 + 1] + bias[n + 1];
                o.z = acc[i][j4 + 2] + bias[n + 2];
                o.w = acc[i][j4 + 3] + bias[n + 3];
                *(float4*)&C[m * N + n] = o;
            }
        }
    } else {
        #pragma unroll
        for (int i = 0; i < 8; i++) {
            const int m  = m0 + ty * 8 + i;
            const int bb = m >> 11;          // batch
            const int nq = m & 2047;         // token
            const float g = gate_full[nq];
            #pragma unroll
            for (int j4 = 0; j4 < 8; j4 += 4) {
                const int n   = n0 + tx * 8 + j4;
                const int sec = n >> 10;      // 0=q 1=k 2=v  (uniform per block)
                const int rem = n & 1023;
                const int h   = rem >> 6;
                const int jd  = rem & 63;
                float4 o;
                o.x = acc[i][j4 + 0] + bias[n + 0];
                o.y = acc[i][j4 + 1] + bias[n + 1];
                o.z = acc[i][j4 + 2] + bias[n + 2];
                o.w = acc[i][j4 + 3] + bias[n + 3];
                float* dst;
                if (sec == 0)      dst = qw;
                else if (sec == 1) dst = kw;
                else { dst = vw; o.x *= g; o.y *= g; o.z *= g; o.w *= g; }
                *(float4*)&dst[(((bb << 4) + h) * NTOK + nq) * DHEAD + jd] = o;
            }
        }
    }
}

// ---------------------------------------------------------------- flash attention
// grid (32 qtiles, 32 bh). 256 threads: r=t>>2 (query row in 64-tile), c=t&3 (16-wide d-chunk).
// Online softmax with defer-rescale threshold (T13): rescale only when the
// running max grows by >8; exp argument stays bounded by 8 (p <= e^8), fp32-safe.
__global__ __launch_bounds__(256)
void attn_kernel(const float* __restrict__ qws, const float* __restrict__ kws,
                 const float* __restrict__ vws, const float* __restrict__ col_bias,
                 float* __restrict__ att)
{
    __shared__ float Ks[64][64];
    __shared__ float Vs[64][64];
    __shared__ float CB[64];

    const int t  = threadIdx.x;
    const int r  = t >> 2;
    const int c  = t & 3;
    const int qt = blockIdx.x;        // 0..31
    const int bh = blockIdx.y;        // 0..31
    const int bhbase = bh * (NTOK * DHEAD);
    const int q_row  = qt * 64 + r;

    float qv[16];
    #pragma unroll
    for (int i = 0; i < 4; i++)
        *(float4*)&qv[4 * i] =
            *(const float4*)&qws[bhbase + q_row * DHEAD + c * 16 + 4 * i];

    float mrun = -INFINITY, lrun = 0.0f;
    float acc[16] = {};

    for (int kt = 0; kt < NTOK; kt += 64) {
        __syncthreads();
        const float4* kp = (const float4*)&kws[bhbase + kt * DHEAD];
        const float4* vp = (const float4*)&vws[bhbase + kt * DHEAD];
        #pragma unroll
        for (int i = 0; i < 4; i++) {
            ((float4*)Ks)[t + i * 256] = kp[t + i * 256];
            ((float4*)Vs)[t + i * 256] = vp[t + i * 256];
        }
        if (t < 64) CB[t] = col_bias[kt + t];
        __syncthreads();

        for (int key = 0; key < 64; key++) {
            float4 k0 = *(const float4*)&Ks[key][c * 16 + 0];
            float4 k1 = *(const float4*)&Ks[key][c * 16 + 4];
            float4 k2 = *(const float4*)&Ks[key][c * 16 + 8];
            float4 k3 = *(const float4*)&Ks[key][c * 16 + 12];
            float part = qv[0]*k0.x + qv[1]*k0.y + qv[2]*k0.z + qv[3]*k0.w
                       + qv[4]*k1.x + qv[5]*k1.y + qv[6]*k1.z + qv[7]*k1.w
                       + qv[8]*k2.x + qv[9]*k2.y + qv[10]*k2.z + qv[11]*k2.w
                       + qv[12]*k3.x + qv[13]*k3.y + qv[14]*k3.z + qv[15]*k3.w;
            part += __shfl_xor(part, 1);
            part += __shfl_xor(part, 2);
            const float s = part * 0.125f + CB[key];

            float p;
            if (s > mrun + 8.0f) {           // rare after warmup (T13)
                const float f = __expf(mrun - s);   // exp(-inf)=0 on first key
                lrun = lrun * f + 1.0f;
                #pragma unroll
                for (int i = 0; i < 16; i++) acc[i] *= f;
                mrun = s;
                p = 1.0f;
            } else {
                p = __expf(s - mrun);        // bounded by e^8 ~ 2981
                lrun += p;
            }

            float4 v0 = *(const float4*)&Vs[key][c * 16 + 0];
            float4 v1 = *(const float4*)&Vs[key][c * 16 + 4];
            float4 v2 = *(const float4*)&Vs[key][c * 16 + 8];
            float4 v3 = *(const float4*)&Vs[key][c * 16 + 12];
            acc[0]  = fmaf(p, v0.x, acc[0]);  acc[1]  = fmaf(p, v0.y, acc[1]);
            acc[2]  = fmaf(p, v0.z, acc[2]);  acc[3]  = fmaf(p, v0.w, acc[3]);
            acc[4]  = fmaf(p, v1.x, acc[4]);  acc[5]  = fmaf(p, v1.y, acc[5]);
            acc[6]  = fmaf(p, v1.z, acc[6]);  acc[7]  = fmaf(p, v1.w, acc[7]);
            acc[8]  = fmaf(p, v2.x, acc[8]);  acc[9]  = fmaf(p, v2.y, acc[9]);
            acc[10] = fmaf(p, v2.z, acc[10]); acc[11] = fmaf(p, v2.w, acc[11]);
            acc[12] = fmaf(p, v3.x, acc[12]); acc[13] = fmaf(p, v3.y, acc[13]);
            acc[14] = fmaf(p, v3.z, acc[14]); acc[15] = fmaf(p, v3.w, acc[15]);
        }
    }

    const float inv = 1.0f / lrun;
    const int b = bh >> 4, h = bh & 15;
    // att layout: [B, N, D] with D index = h*64 + c*16 + j
    const int o = ((b * NTOK) + (qt * 64 + r)) * DMODEL + h * DHEAD + c * 16;
    #pragma unroll
    for (int i = 0; i < 4; i++) {
        float4 w;
        w.x = acc[4 * i + 0] * inv; w.y = acc[4 * i + 1] * inv;
        w.z = acc[4 * i + 2] * inv; w.w = acc[4 * i + 3] * inv;
        *(float4*)&att[o + 4 * i] = w;
    }
}

// ---------------------------------------------------------------- launch
extern "C" void kernel_launch(void* const* d_in, const int* in_sizes, int n_in,
                              void* d_out, int out_size, void* d_ws, size_t ws_size,
                              hipStream_t stream)
{
    const float* x         = (const float*)d_in[0];
    // d_in[1] = n_ctx (int, fixed 1024)
    const float* ctx_ppr   = (const float*)d_in[2];
    const float* ctx_delta = (const float*)d_in[3];
    const float* ctx_trust = (const float*)d_in[4];
    const float* W_in      = (const float*)d_in[5];
    const float* b_in      = (const float*)d_in[6];
    const float* W_out     = (const float*)d_in[7];
    const float* b_out     = (const float*)d_in[8];
    const float* alpha     = (const float*)d_in[9];
    const float* tscale    = (const float*)d_in[10];
    const float* Wd1       = (const float*)d_in[11];
    const float* bd1       = (const float*)d_in[12];
    const float* Wd2       = (const float*)d_in[13];
    const float* bd2       = (const float*)d_in[14];
    float* out = (float*)d_out;

    float* ws = (float*)d_ws;
    float* gate_full = ws;                       // 2048
    float* col_bias  = ws + 2048;                // 2048
    float* qw        = ws + 4096;                // 4,194,304 each
    float* kw        = qw + 4194304;
    float* vw        = kw + 4194304;
    float* att       = vw + 4194304;             // total ~67 MB

    bias_kernel<<<NTOK, 256, 0, stream>>>(ctx_ppr, ctx_delta, ctx_trust, alpha, tscale,
                                          Wd1, bd1, Wd2, bd2, gate_full, col_bias);
    gemm_bt<1><<<dim3(24, 32), 256, 0, stream>>>(x, W_in, b_in, nullptr,
                                                 qw, kw, vw, gate_full,
                                                 BTOT, 3 * DMODEL, DMODEL);
    attn_kernel<<<dim3(32, 32), 256, 0, stream>>>(qw, kw, vw, col_bias, att);
    gemm_bt<0><<<dim3(8, 32), 256, 0, stream>>>(att, W_out, b_out, out,
                                                nullptr, nullptr, nullptr, nullptr,
                                                BTOT, DMODEL, DMODEL);
}

// Round 4
// 794.961 us; speedup vs baseline: 1.7119x; 1.7119x over previous
//
#include <hip/hip_runtime.h>
#include <hip/hip_bf16.h>
#include <math.h>

// B=2, N=2048, D=1024, H=16, d=64, n_ctx=1024, P=256.
// Pipeline: bias -> QKV gemm (fp32 math, epilogue splits Q,K to bf16 hi/lo; V fp32 gated)
//           -> V transpose+split -> MFMA flash attention (split-bf16 3-term) -> out-proj gemm.

#define NTOK 2048
#define DMODEL 1024
#define NHEAD 16
#define DHEAD 64
#define NCTX 1024
#define BTOT 4096

typedef __attribute__((ext_vector_type(8))) short  s8v;    // 8 bf16 bits (4 VGPR) MFMA operand
typedef __attribute__((ext_vector_type(4))) float  f4v;    // MFMA accumulator
typedef __attribute__((ext_vector_type(4))) ushort us4;
typedef __attribute__((ext_vector_type(8))) ushort us8;

// RNE float->bf16 bits and back (bit tricks; self-consistent hi/lo split)
__device__ __forceinline__ ushort f2bf(float x) {
    unsigned b = __float_as_uint(x);
    return (ushort)((b + 0x7FFFu + ((b >> 16) & 1u)) >> 16);
}
__device__ __forceinline__ float bf2f(ushort u) {
    return __uint_as_float(((unsigned)u) << 16);
}

// global_load_lds width 16: linear LDS dest (wave-uniform base + lane*16), per-lane global src
#define GLDS16(gsrc, ldst) __builtin_amdgcn_global_load_lds(                              \
    (__attribute__((address_space(1))) unsigned int*)(gsrc),                              \
    (__attribute__((address_space(3))) unsigned int*)(ldst), 16, 0, 0)

// ---------------------------------------------------------------- bias kernel (unchanged)
__global__ __launch_bounds__(256)
void bias_kernel(const float* __restrict__ ctx_ppr, const float* __restrict__ ctx_delta,
                 const float* __restrict__ ctx_trust,
                 const float* __restrict__ alpha, const float* __restrict__ tscale,
                 const float* __restrict__ Wd1, const float* __restrict__ bd1,
                 const float* __restrict__ Wd2, const float* __restrict__ bd2,
                 float* __restrict__ gate_full, float* __restrict__ col_bias)
{
    const int i = blockIdx.x;
    const int t = threadIdx.x;
    if (i >= NCTX) {
        if (t == 0) { gate_full[i] = 1.0f; col_bias[i] = 0.0f; }
        return;
    }
    __shared__ float drow[256];
    __shared__ float red[256];
    drow[t] = ctx_delta[i * 256 + t];
    __syncthreads();

    float partial = 0.0f;
    #pragma unroll
    for (int jj = 0; jj < 2; jj++) {
        const int j = t + jj * 256;
        float s = bd1[j];
        const float4* wrow = (const float4*)&Wd1[j * 256];
        const float4* dr   = (const float4*)drow;
        #pragma unroll 8
        for (int p = 0; p < 64; p++) {
            float4 w = wrow[p], dd = dr[p];
            s += w.x * dd.x + w.y * dd.y + w.z * dd.z + w.w * dd.w;
        }
        float g = 0.5f * s * (1.0f + erff(s * 0.70710678118654752f));
        partial += g * Wd2[j];
    }
    red[t] = partial;
    __syncthreads();
    for (int off = 128; off > 0; off >>= 1) {
        if (t < off) red[t] += red[t + off];
        __syncthreads();
    }
    if (t == 0) {
        float ppr = fmaxf(ctx_ppr[i], 1e-8f);
        col_bias[i]  = alpha[0] * logf(ppr) + (red[0] + bd2[0]);
        gate_full[i] = 1.0f / (1.0f + __expf(-(tscale[0] * ctx_trust[i])));
    }
}

// ---------------------------------------------------------------- GEMM  C = A @ B^T + bias
// EPI=0: plain fp32 out.  EPI=1: q,k -> bf16 hi/lo split [bh][n][64]; v -> fp32 gated.
template<int EPI>
__global__ __launch_bounds__(256)
void gemm_bt(const float* __restrict__ A, const float* __restrict__ B,
             const float* __restrict__ bias, float* __restrict__ C,
             ushort* __restrict__ qh, ushort* __restrict__ ql,
             ushort* __restrict__ kh, ushort* __restrict__ kl,
             float* __restrict__ vw,
             const float* __restrict__ gate_full, int M, int N, int K)
{
    __shared__ float As[16][132];
    __shared__ float Bs[16][132];
    const int t  = threadIdx.x;
    const int tx = t & 15, ty = t >> 4;
    const int m0 = blockIdx.y * 128, n0 = blockIdx.x * 128;
    const int lr = t >> 2, lc = (t & 3) * 4;

    float acc[8][8] = {};
    float4 pva[2], pvb[2];

    #pragma unroll
    for (int i = 0; i < 2; i++) {
        const int row = lr + i * 64;
        pva[i] = *(const float4*)&A[(m0 + row) * K + lc];
        pvb[i] = *(const float4*)&B[(n0 + row) * K + lc];
    }

    for (int k0 = 0; k0 < K; k0 += 16) {
        __syncthreads();
        #pragma unroll
        for (int i = 0; i < 2; i++) {
            const int row = lr + i * 64;
            As[lc + 0][row] = pva[i].x; As[lc + 1][row] = pva[i].y;
            As[lc + 2][row] = pva[i].z; As[lc + 3][row] = pva[i].w;
            Bs[lc + 0][row] = pvb[i].x; Bs[lc + 1][row] = pvb[i].y;
            Bs[lc + 2][row] = pvb[i].z; Bs[lc + 3][row] = pvb[i].w;
        }
        __syncthreads();
        if (k0 + 16 < K) {
            #pragma unroll
            for (int i = 0; i < 2; i++) {
                const int row = lr + i * 64;
                pva[i] = *(const float4*)&A[(m0 + row) * K + k0 + 16 + lc];
                pvb[i] = *(const float4*)&B[(n0 + row) * K + k0 + 16 + lc];
            }
        }
        #pragma unroll
        for (int k = 0; k < 16; k++) {
            float a[8], b[8];
            *(float4*)&a[0] = *(const float4*)&As[k][ty * 8];
            *(float4*)&a[4] = *(const float4*)&As[k][ty * 8 + 4];
            *(float4*)&b[0] = *(const float4*)&Bs[k][tx * 8];
            *(float4*)&b[4] = *(const float4*)&Bs[k][tx * 8 + 4];
            #pragma unroll
            for (int i = 0; i < 8; i++)
                #pragma unroll
                for (int j = 0; j < 8; j++)
                    acc[i][j] = fmaf(a[i], b[j], acc[i][j]);
        }
    }

    if (EPI == 0) {
        #pragma unroll
        for (int i = 0; i < 8; i++) {
            const int m = m0 + ty * 8 + i;
            #pragma unroll
            for (int j4 = 0; j4 < 8; j4 += 4) {
                const int n = n0 + tx * 8 + j4;
                float4 o;
                o.x = acc[i][j4 + 0] + bias[n + 0];
                o.y = acc[i][j4 + 1] + bias[n + 1];
                o.z = acc[i][j4 + 2] + bias[n + 2];
                o.w = acc[i][j4 + 3] + bias[n + 3];
                *(float4*)&C[m * N + n] = o;
            }
        }
    } else {
        #pragma unroll
        for (int i = 0; i < 8; i++) {
            const int m  = m0 + ty * 8 + i;
            const int bb = m >> 11;
            const int nq = m & 2047;
            const float g = gate_full[nq];
            #pragma unroll
            for (int j4 = 0; j4 < 8; j4 += 4) {
                const int n   = n0 + tx * 8 + j4;
                const int sec = n >> 10;
                const int rem = n & 1023;
                const int h   = rem >> 6;
                const int jd  = rem & 63;
                float4 o;
                o.x = acc[i][j4 + 0] + bias[n + 0];
                o.y = acc[i][j4 + 1] + bias[n + 1];
                o.z = acc[i][j4 + 2] + bias[n + 2];
                o.w = acc[i][j4 + 3] + bias[n + 3];
                const size_t base = (((size_t)((bb << 4) + h)) * NTOK + nq) * DHEAD + jd;
                if (sec == 2) {
                    o.x *= g; o.y *= g; o.z *= g; o.w *= g;
                    *(float4*)&vw[base] = o;
                } else {
                    ushort* dh = sec ? kh : qh;
                    ushort* dl = sec ? kl : ql;
                    us4 hv, lv;
                    ushort hb;
                    hb = f2bf(o.x); hv[0] = hb; lv[0] = f2bf(o.x - bf2f(hb));
                    hb = f2bf(o.y); hv[1] = hb; lv[1] = f2bf(o.y - bf2f(hb));
                    hb = f2bf(o.z); hv[2] = hb; lv[2] = f2bf(o.z - bf2f(hb));
                    hb = f2bf(o.w); hv[3] = hb; lv[3] = f2bf(o.w - bf2f(hb));
                    *(us4*)&dh[base] = hv;
                    *(us4*)&dl[base] = lv;
                }
            }
        }
    }
}

// ---------------------------------------------------------------- V transpose + split
// vw [bh][2048][64] fp32 -> vth/vtl [bh][64][2048] bf16 hi/lo
__global__ __launch_bounds__(256)
void vtrans(const float* __restrict__ vw, ushort* __restrict__ vth, ushort* __restrict__ vtl)
{
    __shared__ float T[64][65];
    const int kt = blockIdx.x, bh = blockIdx.y;
    const int t = threadIdx.x;
    const float* src = vw + ((size_t)bh * NTOK + kt * 64) * DHEAD;
    {
        const int tok = t >> 2, c0 = (t & 3) * 16;
        #pragma unroll
        for (int j = 0; j < 4; j++) {
            float4 v = *(const float4*)&src[tok * 64 + c0 + 4 * j];
            T[tok][c0 + 4*j + 0] = v.x; T[tok][c0 + 4*j + 1] = v.y;
            T[tok][c0 + 4*j + 2] = v.z; T[tok][c0 + 4*j + 3] = v.w;
        }
    }
    __syncthreads();
    {
        const int d = t >> 2, k0 = (t & 3) * 16;
        const size_t ob = ((size_t)bh * DHEAD + d) * NTOK + kt * 64 + k0;
        #pragma unroll
        for (int half = 0; half < 2; half++) {
            us8 hv, lv;
            #pragma unroll
            for (int e = 0; e < 8; e++) {
                float x = T[k0 + half * 8 + e][d];
                ushort hb = f2bf(x);
                hv[e] = hb; lv[e] = f2bf(x - bf2f(hb));
            }
            *(us8*)&vth[ob + half * 8] = hv;
            *(us8*)&vtl[ob + half * 8] = lv;
        }
    }
}

// ---------------------------------------------------------------- MFMA flash attention
// Block = 4 waves = one (bh, 64 q-rows). Wave owns 16 q-rows.
// Split-bf16 3-term for QK^T and PV. K/Vt tiles (64 keys) in LDS, XOR-swizzled
// (chunk ^= row&7 on 16B granules) for conflict-free ds_read_b128 frags.
// global_load_lds: linear LDS dest + inverse-swizzled global source (both-sides rule).
__global__ __launch_bounds__(256)
void attn_mfma(const ushort* __restrict__ qh, const ushort* __restrict__ ql,
               const ushort* __restrict__ kh, const ushort* __restrict__ kl,
               const ushort* __restrict__ vth, const ushort* __restrict__ vtl,
               const float* __restrict__ col_bias, float* __restrict__ att)
{
    __shared__ ushort Kh_s[4096], Kl_s[4096], Vh_s[4096], Vl_s[4096];  // [64 rows][64 cols]
    __shared__ ushort Ph_s[4][1024], Pl_s[4][1024];                    // per-wave P [16][64]
    __shared__ float CBs[64];

    const int t = threadIdx.x, lane = t & 63, wid = t >> 6;
    // XCD-aware bijective remap: 1024 blocks, 128 consecutive works per XCD
    const int lin = blockIdx.y * gridDim.x + blockIdx.x;
    const int w   = (lin & 7) * 128 + (lin >> 3);
    const int bh  = w >> 5, qt = w & 31;

    const size_t qkbase = (size_t)bh * (NTOK * DHEAD);
    const size_t vtbase = (size_t)bh * (DHEAD * NTOK);
    const int l15 = lane & 15, l4 = lane >> 4;
    const int q0 = qt * 64 + wid * 16;

    // Q fragments in registers: lane -> Q[q0+l15][32s + 8*l4 + 0..7]
    s8v qfh[2], qfl[2];
    #pragma unroll
    for (int s = 0; s < 2; s++) {
        const size_t off = qkbase + (size_t)(q0 + l15) * 64 + 32 * s + 8 * l4;
        qfh[s] = *(const s8v*)&qh[off];
        qfl[s] = *(const s8v*)&ql[off];
    }

    f4v oacc[4];
    #pragma unroll
    for (int g = 0; g < 4; g++)
        #pragma unroll
        for (int r = 0; r < 4; r++) oacc[g][r] = 0.0f;
    float mrow[4] = {-INFINITY, -INFINITY, -INFINITY, -INFINITY};
    float srow[4] = {0.0f, 0.0f, 0.0f, 0.0f};

    for (int kt = 0; kt < NTOK; kt += 64) {
        __syncthreads();
        // ---- stage K/Vt tile: each wave stages one 8KB plane (8 x 1KB issues)
        if (wid < 2) {
            const ushort* sp = wid ? kl : kh;
            ushort* dp = wid ? Kl_s : Kh_s;
            #pragma unroll
            for (int i = 0; i < 8; i++) {
                const int row = i * 8 + (lane >> 3);
                const int sc  = ((lane & 7) ^ (row & 7)) * 8;   // inverse swizzle on source
                GLDS16(sp + qkbase + (size_t)(kt + row) * 64 + sc, dp + i * 512);
            }
        } else {
            const ushort* sp = (wid == 2) ? vth : vtl;
            ushort* dp = (wid == 2) ? Vh_s : Vl_s;
            #pragma unroll
            for (int i = 0; i < 8; i++) {
                const int row = i * 8 + (lane >> 3);            // d index
                const int sc  = ((lane & 7) ^ (row & 7)) * 8;
                GLDS16(sp + vtbase + (size_t)row * NTOK + kt + sc, dp + i * 512);
            }
        }
        if (t < 64) CBs[t] = col_bias[kt + t];
        __syncthreads();   // drains vmcnt -> staged data visible

        // ---- QK^T: S[16q x 64keys], 3-term split
        f4v sa[4];
        #pragma unroll
        for (int g = 0; g < 4; g++)
            #pragma unroll
            for (int r = 0; r < 4; r++) sa[g][r] = 0.0f;
        #pragma unroll
        for (int s = 0; s < 2; s++) {
            #pragma unroll
            for (int g = 0; g < 4; g++) {
                const int row = 16 * g + l15;                     // key row
                const int csw = ((4 * s + l4) ^ (row & 7)) * 8;   // swizzled elem col
                s8v bh_ = *(const s8v*)&Kh_s[row * 64 + csw];
                s8v bl_ = *(const s8v*)&Kl_s[row * 64 + csw];
                sa[g] = __builtin_amdgcn_mfma_f32_16x16x32_bf16(qfh[s], bh_, sa[g], 0, 0, 0);
                sa[g] = __builtin_amdgcn_mfma_f32_16x16x32_bf16(qfh[s], bl_, sa[g], 0, 0, 0);
                sa[g] = __builtin_amdgcn_mfma_f32_16x16x32_bf16(qfl[s], bh_, sa[g], 0, 0, 0);
            }
        }

        // ---- online softmax (row = l4*4 + r, col = 16g + l15)
        float cb[4];
        #pragma unroll
        for (int g = 0; g < 4; g++) cb[g] = CBs[16 * g + l15];

        float p[4][4], fsc[4];
        #pragma unroll
        for (int r = 0; r < 4; r++) {
            float s0 = sa[0][r] * 0.125f + cb[0];
            float s1 = sa[1][r] * 0.125f + cb[1];
            float s2 = sa[2][r] * 0.125f + cb[2];
            float s3 = sa[3][r] * 0.125f + cb[3];
            float mx = fmaxf(fmaxf(s0, s1), fmaxf(s2, s3));
            mx = fmaxf(mx, __shfl_xor(mx, 1));
            mx = fmaxf(mx, __shfl_xor(mx, 2));
            mx = fmaxf(mx, __shfl_xor(mx, 4));
            mx = fmaxf(mx, __shfl_xor(mx, 8));
            const float mnew = fmaxf(mrow[r], mx);
            const float f = __expf(mrow[r] - mnew);   // first tile: exp(-inf)=0
            mrow[r] = mnew;
            p[0][r] = __expf(s0 - mnew);
            p[1][r] = __expf(s1 - mnew);
            p[2][r] = __expf(s2 - mnew);
            p[3][r] = __expf(s3 - mnew);
            float ts = p[0][r] + p[1][r] + p[2][r] + p[3][r];
            ts += __shfl_xor(ts, 1);
            ts += __shfl_xor(ts, 2);
            ts += __shfl_xor(ts, 4);
            ts += __shfl_xor(ts, 8);
            srow[r] = srow[r] * f + ts;
            fsc[r] = f;
        }
        #pragma unroll
        for (int g = 0; g < 4; g++)
            #pragma unroll
            for (int r = 0; r < 4; r++) oacc[g][r] *= fsc[r];

        // ---- P -> bf16 hi/lo into per-wave LDS (swizzled), no barrier needed
        #pragma unroll
        for (int g = 0; g < 4; g++) {
            #pragma unroll
            for (int r = 0; r < 4; r++) {
                const int prow = l4 * 4 + r;
                const int pcol = 16 * g + l15;
                const int pe = prow * 64 + ((((pcol >> 3) ^ (prow & 7))) << 3) + (pcol & 7);
                const float pv = p[g][r];
                const ushort hb = f2bf(pv);
                Ph_s[wid][pe] = hb;
                Pl_s[wid][pe] = f2bf(pv - bf2f(hb));
            }
        }

        // ---- PV: O[16q x 64d] += P @ V, 3-term split
        #pragma unroll
        for (int s = 0; s < 2; s++) {
            const int pr  = l15;                                  // q row
            const int pcb = ((4 * s + l4) ^ (pr & 7)) * 8;
            s8v pah = *(const s8v*)&Ph_s[wid][pr * 64 + pcb];
            s8v pal = *(const s8v*)&Pl_s[wid][pr * 64 + pcb];
            #pragma unroll
            for (int g = 0; g < 4; g++) {
                const int vrow = 16 * g + l15;                    // d row of Vt
                const int vcb  = ((4 * s + l4) ^ (vrow & 7)) * 8;
                s8v vbh = *(const s8v*)&Vh_s[vrow * 64 + vcb];
                s8v vbl = *(const s8v*)&Vl_s[vrow * 64 + vcb];
                oacc[g] = __builtin_amdgcn_mfma_f32_16x16x32_bf16(pah, vbh, oacc[g], 0, 0, 0);
                oacc[g] = __builtin_amdgcn_mfma_f32_16x16x32_bf16(pah, vbl, oacc[g], 0, 0, 0);
                oacc[g] = __builtin_amdgcn_mfma_f32_16x16x32_bf16(pal, vbh, oacc[g], 0, 0, 0);
            }
        }
    }

    // ---- epilogue: normalize, write att [B][N][D]
    const int b = bh >> 4, h = bh & 15;
    #pragma unroll
    for (int r = 0; r < 4; r++) {
        const float inv = 1.0f / srow[r];
        const int row = q0 + l4 * 4 + r;
        const size_t o = ((size_t)(b * NTOK + row)) * DMODEL + h * DHEAD + l15;
        #pragma unroll
        for (int g = 0; g < 4; g++)
            att[o + 16 * g] = oacc[g][r] * inv;
    }
}

// ---------------------------------------------------------------- launch
extern "C" void kernel_launch(void* const* d_in, const int* in_sizes, int n_in,
                              void* d_out, int out_size, void* d_ws, size_t ws_size,
                              hipStream_t stream)
{
    const float* x         = (const float*)d_in[0];
    const float* ctx_ppr   = (const float*)d_in[2];
    const float* ctx_delta = (const float*)d_in[3];
    const float* ctx_trust = (const float*)d_in[4];
    const float* W_in      = (const float*)d_in[5];
    const float* b_in      = (const float*)d_in[6];
    const float* W_out     = (const float*)d_in[7];
    const float* b_out     = (const float*)d_in[8];
    const float* alpha     = (const float*)d_in[9];
    const float* tscale    = (const float*)d_in[10];
    const float* Wd1       = (const float*)d_in[11];
    const float* bd1       = (const float*)d_in[12];
    const float* Wd2       = (const float*)d_in[13];
    const float* bd2       = (const float*)d_in[14];
    float* out = (float*)d_out;

    float* ws = (float*)d_ws;
    float* gate_full = ws;                         // 2048 f
    float* col_bias  = ws + 2048;                  // 2048 f
    float* att       = ws + 4096;                  // 4M f  (aliased with vw: vw is dead
    float* vw        = att;                        //        before attn writes att)
    ushort* ub  = (ushort*)(ws + 4096 + 4194304);
    ushort* qh  = ub;                              // 4M ushort each
    ushort* ql  = qh  + 4194304;
    ushort* kh  = ql  + 4194304;
    ushort* kl  = kh  + 4194304;
    ushort* vth = kl  + 4194304;
    ushort* vtl = vth + 4194304;                   // total ws = 67.1 MB (same as round 2)

    bias_kernel<<<NTOK, 256, 0, stream>>>(ctx_ppr, ctx_delta, ctx_trust, alpha, tscale,
                                          Wd1, bd1, Wd2, bd2, gate_full, col_bias);
    gemm_bt<1><<<dim3(24, 32), 256, 0, stream>>>(x, W_in, b_in, nullptr,
                                                 qh, ql, kh, kl, vw, gate_full,
                                                 BTOT, 3 * DMODEL, DMODEL);
    vtrans<<<dim3(32, 32), 256, 0, stream>>>(vw, vth, vtl);
    attn_mfma<<<dim3(32, 32), 256, 0, stream>>>(qh, ql, kh, kl, vth, vtl, col_bias, att);
    gemm_bt<0><<<dim3(8, 32), 256, 0, stream>>>(att, W_out, b_out, out,
                                                nullptr, nullptr, nullptr, nullptr, nullptr,
                                                nullptr, BTOT, DMODEL, DMODEL);
}

// Round 5
// 495.918 us; speedup vs baseline: 2.7442x; 1.6030x over previous
//
#include <hip/hip_runtime.h>
#include <hip/hip_bf16.h>
#include <math.h>

// B=2, N=2048, D=1024, H=16, d=64, n_ctx=1024, P=256.
// Pipeline: bias -> split x/W_in/W_out to bf16 hi/lo -> QKV MFMA gemm (3-term split-bf16,
// epilogue scatters q/k hi/lo + V^T hi/lo gated) -> MFMA flash attention (emits att hi/lo)
// -> out-proj MFMA gemm.

#define NTOK 2048
#define DMODEL 1024
#define NHEAD 16
#define DHEAD 64
#define NCTX 1024
#define BTOT 4096

typedef __attribute__((ext_vector_type(8))) short  s8v;    // 8 bf16 bits (4 VGPR) MFMA operand
typedef __attribute__((ext_vector_type(4))) float  f4v;    // MFMA accumulator
typedef __attribute__((ext_vector_type(4))) ushort us4;
typedef __attribute__((ext_vector_type(8))) ushort us8;

__device__ __forceinline__ ushort f2bf(float x) {
    unsigned b = __float_as_uint(x);
    return (ushort)((b + 0x7FFFu + ((b >> 16) & 1u)) >> 16);
}
__device__ __forceinline__ float bf2f(ushort u) {
    return __uint_as_float(((unsigned)u) << 16);
}

// global_load_lds width 16: linear LDS dest (wave-uniform base + lane*16), per-lane global src
#define GLDS16(gsrc, ldst) __builtin_amdgcn_global_load_lds(                              \
    (__attribute__((address_space(1))) unsigned int*)(gsrc),                              \
    (__attribute__((address_space(3))) unsigned int*)(ldst), 16, 0, 0)

// ---------------------------------------------------------------- bias kernel (unchanged)
__global__ __launch_bounds__(256)
void bias_kernel(const float* __restrict__ ctx_ppr, const float* __restrict__ ctx_delta,
                 const float* __restrict__ ctx_trust,
                 const float* __restrict__ alpha, const float* __restrict__ tscale,
                 const float* __restrict__ Wd1, const float* __restrict__ bd1,
                 const float* __restrict__ Wd2, const float* __restrict__ bd2,
                 float* __restrict__ gate_full, float* __restrict__ col_bias)
{
    const int i = blockIdx.x;
    const int t = threadIdx.x;
    if (i >= NCTX) {
        if (t == 0) { gate_full[i] = 1.0f; col_bias[i] = 0.0f; }
        return;
    }
    __shared__ float drow[256];
    __shared__ float red[256];
    drow[t] = ctx_delta[i * 256 + t];
    __syncthreads();

    float partial = 0.0f;
    #pragma unroll
    for (int jj = 0; jj < 2; jj++) {
        const int j = t + jj * 256;
        float s = bd1[j];
        const float4* wrow = (const float4*)&Wd1[j * 256];
        const float4* dr   = (const float4*)drow;
        #pragma unroll 8
        for (int p = 0; p < 64; p++) {
            float4 w = wrow[p], dd = dr[p];
            s += w.x * dd.x + w.y * dd.y + w.z * dd.z + w.w * dd.w;
        }
        float g = 0.5f * s * (1.0f + erff(s * 0.70710678118654752f));
        partial += g * Wd2[j];
    }
    red[t] = partial;
    __syncthreads();
    for (int off = 128; off > 0; off >>= 1) {
        if (t < off) red[t] += red[t + off];
        __syncthreads();
    }
    if (t == 0) {
        float ppr = fmaxf(ctx_ppr[i], 1e-8f);
        col_bias[i]  = alpha[0] * logf(ppr) + (red[0] + bd2[0]);
        gate_full[i] = 1.0f / (1.0f + __expf(-(tscale[0] * ctx_trust[i])));
    }
}

// ---------------------------------------------------------------- fp32 -> bf16 hi/lo split
__global__ __launch_bounds__(256)
void cvt_split(const float* __restrict__ in, ushort* __restrict__ hi,
               ushort* __restrict__ lo, int n4)
{
    for (int i = blockIdx.x * 256 + threadIdx.x; i < n4; i += gridDim.x * 256) {
        float4 v = ((const float4*)in)[i];
        us4 h, l; ushort hb;
        hb = f2bf(v.x); h[0] = hb; l[0] = f2bf(v.x - bf2f(hb));
        hb = f2bf(v.y); h[1] = hb; l[1] = f2bf(v.y - bf2f(hb));
        hb = f2bf(v.z); h[2] = hb; l[2] = f2bf(v.z - bf2f(hb));
        hb = f2bf(v.w); h[3] = hb; l[3] = f2bf(v.w - bf2f(hb));
        ((us4*)hi)[i] = h; ((us4*)lo)[i] = l;
    }
}

// ---------------------------------------------------------------- split-bf16 MFMA GEMM
// C = A @ B^T (+bias), A [M][K], B [N][K], both as bf16 hi/lo. 3-term Markidis.
// MT: m-fragments per wave (BM = MT*32). BN=128, BK=32. 4 waves in 2x2.
// EPI=0: fp32 C out. EPI=1: scatter q/k hi/lo [bh][tok][64] and V^T hi/lo [bh][64][tok], gated.
template<int MT, int EPI>
__global__ __launch_bounds__(256)
void gemm_mfma(const ushort* __restrict__ Ah, const ushort* __restrict__ Al,
               const ushort* __restrict__ Bh, const ushort* __restrict__ Bl,
               const float* __restrict__ bias, float* __restrict__ C,
               ushort* __restrict__ qh, ushort* __restrict__ ql,
               ushort* __restrict__ kh, ushort* __restrict__ kl,
               ushort* __restrict__ vth, ushort* __restrict__ vtl,
               const float* __restrict__ gate_full, int M, int N, int K)
{
    constexpr int BM = MT * 32;
    __shared__ ushort AhS[BM * 32], AlS[BM * 32], BhS[4096], BlS[4096];

    const int t = threadIdx.x, lane = t & 63, wid = t >> 6;
    const int l15 = lane & 15, l4 = lane >> 4;
    const int wr = wid >> 1, wc = wid & 1;

    // XCD-aware bijective block swizzle (nwg % 8 == 0 for all our grids)
    const int nwg = gridDim.x * gridDim.y;
    const int lin = blockIdx.y * gridDim.x + blockIdx.x;
    const int w   = (lin & 7) * (nwg >> 3) + (lin >> 3);
    const int bx  = w % gridDim.x, by = w / gridDim.x;
    const int m0 = by * BM, n0 = bx * 128;

    f4v acc[MT][4];
    #pragma unroll
    for (int mi = 0; mi < MT; mi++)
        #pragma unroll
        for (int nj = 0; nj < 4; nj++)
            #pragma unroll
            for (int r = 0; r < 4; r++) acc[mi][nj][r] = 0.0f;

    // staging: dest is linear; source chunk carries the inverse swizzle (lane-only, issue-invariant)
    const int srow_l = lane >> 2;
    const int schunk = (lane & 3) ^ ((lane >> 2) & 3) ^ ((lane >> 4) & 3);
    // fragment-read chunk (same swizzle): residual 2-way bank conflict = free
    const int rch = l4 ^ (l15 & 3) ^ ((l15 >> 2) & 3);

    const ushort* sA = (wid == 0) ? Ah : Al;
    const ushort* sB = (wid == 2) ? Bh : Bl;
    ushort* dA = (wid == 0) ? AhS : AlS;
    ushort* dB = (wid == 2) ? BhS : BlS;

    for (int k0 = 0; k0 < K; k0 += 32) {
        __syncthreads();
        if (wid < 2) {
            #pragma unroll
            for (int i = 0; i < BM / 16; i++) {
                const int row = i * 16 + srow_l;
                GLDS16(sA + (size_t)(m0 + row) * K + k0 + schunk * 8, dA + i * 512);
            }
        } else {
            #pragma unroll
            for (int i = 0; i < 8; i++) {
                const int row = i * 16 + srow_l;
                GLDS16(sB + (size_t)(n0 + row) * K + k0 + schunk * 8, dB + i * 512);
            }
        }
        __syncthreads();   // waits vmcnt(0): staged data visible

        s8v afh[MT], afl[MT], bfh[4], bfl[4];
        #pragma unroll
        for (int mi = 0; mi < MT; mi++) {
            const int row = wr * (MT * 16) + mi * 16 + l15;
            afh[mi] = *(const s8v*)&AhS[row * 32 + rch * 8];
            afl[mi] = *(const s8v*)&AlS[row * 32 + rch * 8];
        }
        #pragma unroll
        for (int nj = 0; nj < 4; nj++) {
            const int row = wc * 64 + nj * 16 + l15;
            bfh[nj] = *(const s8v*)&BhS[row * 32 + rch * 8];
            bfl[nj] = *(const s8v*)&BlS[row * 32 + rch * 8];
        }
        #pragma unroll
        for (int mi = 0; mi < MT; mi++)
            #pragma unroll
            for (int nj = 0; nj < 4; nj++) {
                acc[mi][nj] = __builtin_amdgcn_mfma_f32_16x16x32_bf16(afh[mi], bfh[nj], acc[mi][nj], 0, 0, 0);
                acc[mi][nj] = __builtin_amdgcn_mfma_f32_16x16x32_bf16(afh[mi], bfl[nj], acc[mi][nj], 0, 0, 0);
                acc[mi][nj] = __builtin_amdgcn_mfma_f32_16x16x32_bf16(afl[mi], bfh[nj], acc[mi][nj], 0, 0, 0);
            }
    }

    if (EPI == 0) {
        #pragma unroll
        for (int mi = 0; mi < MT; mi++) {
            #pragma unroll
            for (int nj = 0; nj < 4; nj++) {
                const int n = n0 + wc * 64 + nj * 16 + l15;
                const float bn = bias[n];
                #pragma unroll
                for (int r = 0; r < 4; r++) {
                    const int m = m0 + wr * (MT * 16) + mi * 16 + l4 * 4 + r;
                    C[(size_t)m * N + n] = acc[mi][nj][r] + bn;
                }
            }
        }
    } else {
        const int sec = n0 >> 10;   // uniform per block (BN=128 divides 1024)
        #pragma unroll
        for (int mi = 0; mi < MT; mi++) {
            const int mbase = m0 + wr * (MT * 16) + mi * 16 + l4 * 4;
            const int bb = mbase >> 11, tok0 = mbase & 2047;
            #pragma unroll
            for (int nj = 0; nj < 4; nj++) {
                const int n = n0 + wc * 64 + nj * 16 + l15;
                const float bn = bias[n];
                const int rem = n & 1023, h = rem >> 6, jd = rem & 63;
                if (sec == 2) {
                    us4 hv, lv;
                    #pragma unroll
                    for (int r = 0; r < 4; r++) {
                        const float o = (acc[mi][nj][r] + bn) * gate_full[tok0 + r];
                        const ushort hb = f2bf(o);
                        hv[r] = hb; lv[r] = f2bf(o - bf2f(hb));
                    }
                    const size_t vb = ((size_t)((bb << 4) + h) * 64 + jd) * NTOK + tok0;
                    *(us4*)&vth[vb] = hv;
                    *(us4*)&vtl[vb] = lv;
                } else {
                    ushort* dh = sec ? kh : qh;
                    ushort* dl = sec ? kl : ql;
                    #pragma unroll
                    for (int r = 0; r < 4; r++) {
                        const float o = acc[mi][nj][r] + bn;
                        const size_t idx = ((size_t)((bb << 4) + h) * NTOK + (tok0 + r)) * 64 + jd;
                        const ushort hb = f2bf(o);
                        dh[idx] = hb;
                        dl[idx] = f2bf(o - bf2f(hb));
                    }
                }
            }
        }
    }
}

// ---------------------------------------------------------------- MFMA flash attention
// As round 4 (passing) + T13 defer-max + hi/lo bf16 att output for the MFMA out-proj.
__global__ __launch_bounds__(256)
void attn_mfma(const ushort* __restrict__ qh, const ushort* __restrict__ ql,
               const ushort* __restrict__ kh, const ushort* __restrict__ kl,
               const ushort* __restrict__ vth, const ushort* __restrict__ vtl,
               const float* __restrict__ col_bias,
               ushort* __restrict__ atth, ushort* __restrict__ attl)
{
    __shared__ ushort Kh_s[4096], Kl_s[4096], Vh_s[4096], Vl_s[4096];  // [64 rows][64 cols]
    __shared__ ushort Ph_s[4][1024], Pl_s[4][1024];                    // per-wave P [16][64]
    __shared__ float CBs[64];

    const int t = threadIdx.x, lane = t & 63, wid = t >> 6;
    const int lin = blockIdx.y * gridDim.x + blockIdx.x;
    const int w   = (lin & 7) * 128 + (lin >> 3);
    const int bh  = w >> 5, qt = w & 31;

    const size_t qkbase = (size_t)bh * (NTOK * DHEAD);
    const size_t vtbase = (size_t)bh * (DHEAD * NTOK);
    const int l15 = lane & 15, l4 = lane >> 4;
    const int q0 = qt * 64 + wid * 16;

    s8v qfh[2], qfl[2];
    #pragma unroll
    for (int s = 0; s < 2; s++) {
        const size_t off = qkbase + (size_t)(q0 + l15) * 64 + 32 * s + 8 * l4;
        qfh[s] = *(const s8v*)&qh[off];
        qfl[s] = *(const s8v*)&ql[off];
    }

    f4v oacc[4];
    #pragma unroll
    for (int g = 0; g < 4; g++)
        #pragma unroll
        for (int r = 0; r < 4; r++) oacc[g][r] = 0.0f;
    float mrow[4] = {-INFINITY, -INFINITY, -INFINITY, -INFINITY};
    float srow[4] = {0.0f, 0.0f, 0.0f, 0.0f};

    for (int kt = 0; kt < NTOK; kt += 64) {
        __syncthreads();
        if (wid < 2) {
            const ushort* sp = wid ? kl : kh;
            ushort* dp = wid ? Kl_s : Kh_s;
            #pragma unroll
            for (int i = 0; i < 8; i++) {
                const int row = i * 8 + (lane >> 3);
                const int sc  = ((lane & 7) ^ (row & 7)) * 8;
                GLDS16(sp + qkbase + (size_t)(kt + row) * 64 + sc, dp + i * 512);
            }
        } else {
            const ushort* sp = (wid == 2) ? vth : vtl;
            ushort* dp = (wid == 2) ? Vh_s : Vl_s;
            #pragma unroll
            for (int i = 0; i < 8; i++) {
                const int row = i * 8 + (lane >> 3);
                const int sc  = ((lane & 7) ^ (row & 7)) * 8;
                GLDS16(sp + vtbase + (size_t)row * NTOK + kt + sc, dp + i * 512);
            }
        }
        if (t < 64) CBs[t] = col_bias[kt + t];
        __syncthreads();

        // ---- QK^T (3-term)
        f4v sa[4];
        #pragma unroll
        for (int g = 0; g < 4; g++)
            #pragma unroll
            for (int r = 0; r < 4; r++) sa[g][r] = 0.0f;
        #pragma unroll
        for (int s = 0; s < 2; s++) {
            #pragma unroll
            for (int g = 0; g < 4; g++) {
                const int row = 16 * g + l15;
                const int csw = ((4 * s + l4) ^ (row & 7)) * 8;
                s8v bh_ = *(const s8v*)&Kh_s[row * 64 + csw];
                s8v bl_ = *(const s8v*)&Kl_s[row * 64 + csw];
                sa[g] = __builtin_amdgcn_mfma_f32_16x16x32_bf16(qfh[s], bh_, sa[g], 0, 0, 0);
                sa[g] = __builtin_amdgcn_mfma_f32_16x16x32_bf16(qfh[s], bl_, sa[g], 0, 0, 0);
                sa[g] = __builtin_amdgcn_mfma_f32_16x16x32_bf16(qfl[s], bh_, sa[g], 0, 0, 0);
            }
        }

        // ---- online softmax with defer-max (T13): rescale only when max grows >8
        float cb[4];
        #pragma unroll
        for (int g = 0; g < 4; g++) cb[g] = CBs[16 * g + l15];

        float sc_[4][4], mx[4];
        #pragma unroll
        for (int r = 0; r < 4; r++) {
            sc_[0][r] = sa[0][r] * 0.125f + cb[0];
            sc_[1][r] = sa[1][r] * 0.125f + cb[1];
            sc_[2][r] = sa[2][r] * 0.125f + cb[2];
            sc_[3][r] = sa[3][r] * 0.125f + cb[3];
            float m = fmaxf(fmaxf(sc_[0][r], sc_[1][r]), fmaxf(sc_[2][r], sc_[3][r]));
            m = fmaxf(m, __shfl_xor(m, 1));
            m = fmaxf(m, __shfl_xor(m, 2));
            m = fmaxf(m, __shfl_xor(m, 4));
            m = fmaxf(m, __shfl_xor(m, 8));
            mx[r] = m;
        }
        bool need = false;
        #pragma unroll
        for (int r = 0; r < 4; r++) need = need || (mx[r] > mrow[r] + 8.0f);
        if (__any(need)) {
            float fsc[4];
            #pragma unroll
            for (int r = 0; r < 4; r++) {
                const float mnew = fmaxf(mrow[r], mx[r]);
                fsc[r] = __expf(mrow[r] - mnew);   // first tile: exp(-inf)=0
                mrow[r] = mnew;
                srow[r] *= fsc[r];
            }
            #pragma unroll
            for (int g = 0; g < 4; g++)
                #pragma unroll
                for (int r = 0; r < 4; r++) oacc[g][r] *= fsc[r];
        }
        float p[4][4];
        #pragma unroll
        for (int r = 0; r < 4; r++) {
            p[0][r] = __expf(sc_[0][r] - mrow[r]);
            p[1][r] = __expf(sc_[1][r] - mrow[r]);
            p[2][r] = __expf(sc_[2][r] - mrow[r]);
            p[3][r] = __expf(sc_[3][r] - mrow[r]);
            float ts = p[0][r] + p[1][r] + p[2][r] + p[3][r];
            ts += __shfl_xor(ts, 1);
            ts += __shfl_xor(ts, 2);
            ts += __shfl_xor(ts, 4);
            ts += __shfl_xor(ts, 8);
            srow[r] += ts;
        }

        // ---- P -> bf16 hi/lo into per-wave LDS (swizzled)
        #pragma unroll
        for (int g = 0; g < 4; g++) {
            #pragma unroll
            for (int r = 0; r < 4; r++) {
                const int prow = l4 * 4 + r;
                const int pcol = 16 * g + l15;
                const int pe = prow * 64 + ((((pcol >> 3) ^ (prow & 7))) << 3) + (pcol & 7);
                const float pv = p[g][r];
                const ushort hb = f2bf(pv);
                Ph_s[wid][pe] = hb;
                Pl_s[wid][pe] = f2bf(pv - bf2f(hb));
            }
        }

        // ---- PV (3-term)
        #pragma unroll
        for (int s = 0; s < 2; s++) {
            const int pr  = l15;
            const int pcb = ((4 * s + l4) ^ (pr & 7)) * 8;
            s8v pah = *(const s8v*)&Ph_s[wid][pr * 64 + pcb];
            s8v pal = *(const s8v*)&Pl_s[wid][pr * 64 + pcb];
            #pragma unroll
            for (int g = 0; g < 4; g++) {
                const int vrow = 16 * g + l15;
                const int vcb  = ((4 * s + l4) ^ (vrow & 7)) * 8;
                s8v vbh = *(const s8v*)&Vh_s[vrow * 64 + vcb];
                s8v vbl = *(const s8v*)&Vl_s[vrow * 64 + vcb];
                oacc[g] = __builtin_amdgcn_mfma_f32_16x16x32_bf16(pah, vbh, oacc[g], 0, 0, 0);
                oacc[g] = __builtin_amdgcn_mfma_f32_16x16x32_bf16(pah, vbl, oacc[g], 0, 0, 0);
                oacc[g] = __builtin_amdgcn_mfma_f32_16x16x32_bf16(pal, vbh, oacc[g], 0, 0, 0);
            }
        }
    }

    // ---- epilogue: normalize, emit att as bf16 hi/lo [B][N][D]
    const int b = bh >> 4, h = bh & 15;
    #pragma unroll
    for (int r = 0; r < 4; r++) {
        const float inv = 1.0f / srow[r];
        const int row = q0 + l4 * 4 + r;
        const size_t o = ((size_t)(b * NTOK + row)) * DMODEL + h * DHEAD + l15;
        #pragma unroll
        for (int g = 0; g < 4; g++) {
            const float v = oacc[g][r] * inv;
            const ushort hb = f2bf(v);
            atth[o + 16 * g] = hb;
            attl[o + 16 * g] = f2bf(v - bf2f(hb));
        }
    }
}

// ---------------------------------------------------------------- launch
extern "C" void kernel_launch(void* const* d_in, const int* in_sizes, int n_in,
                              void* d_out, int out_size, void* d_ws, size_t ws_size,
                              hipStream_t stream)
{
    const float* x         = (const float*)d_in[0];
    const float* ctx_ppr   = (const float*)d_in[2];
    const float* ctx_delta = (const float*)d_in[3];
    const float* ctx_trust = (const float*)d_in[4];
    const float* W_in      = (const float*)d_in[5];
    const float* b_in      = (const float*)d_in[6];
    const float* W_out     = (const float*)d_in[7];
    const float* b_out     = (const float*)d_in[8];
    const float* alpha     = (const float*)d_in[9];
    const float* tscale    = (const float*)d_in[10];
    const float* Wd1       = (const float*)d_in[11];
    const float* bd1       = (const float*)d_in[12];
    const float* Wd2       = (const float*)d_in[13];
    const float* bd2       = (const float*)d_in[14];
    float* out = (float*)d_out;

    float* ws = (float*)d_ws;
    float* gate_full = ws;                          // 2048 f
    float* col_bias  = ws + 2048;                   // 2048 f
    ushort* u = (ushort*)(ws + 4096);
    ushort* xh  = u;  u += 4194304;                 // aliased: atth after attn
    ushort* xl  = u;  u += 4194304;                 // aliased: attl
    ushort* wih = u;  u += 3145728;
    ushort* wil = u;  u += 3145728;
    ushort* woh = u;  u += 1048576;
    ushort* wol = u;  u += 1048576;
    ushort* qh  = u;  u += 4194304;
    ushort* ql  = u;  u += 4194304;
    ushort* kh  = u;  u += 4194304;
    ushort* kl  = u;  u += 4194304;
    ushort* vth = u;  u += 4194304;
    ushort* vtl = u;  u += 4194304;                 // total ~84 MB

    bias_kernel<<<NTOK, 256, 0, stream>>>(ctx_ppr, ctx_delta, ctx_trust, alpha, tscale,
                                          Wd1, bd1, Wd2, bd2, gate_full, col_bias);
    cvt_split<<<1024, 256, 0, stream>>>(x,     xh,  xl,  1048576);
    cvt_split<<<768,  256, 0, stream>>>(W_in,  wih, wil, 786432);
    cvt_split<<<256,  256, 0, stream>>>(W_out, woh, wol, 262144);

    gemm_mfma<4, 1><<<dim3(24, 32), 256, 0, stream>>>(xh, xl, wih, wil, b_in, nullptr,
                                                      qh, ql, kh, kl, vth, vtl, gate_full,
                                                      BTOT, 3 * DMODEL, DMODEL);
    attn_mfma<<<dim3(32, 32), 256, 0, stream>>>(qh, ql, kh, kl, vth, vtl, col_bias,
                                                xh, xl);   // att hi/lo reuses x buffers
    gemm_mfma<2, 0><<<dim3(8, 64), 256, 0, stream>>>(xh, xl, woh, wol, b_out, out,
                                                     nullptr, nullptr, nullptr, nullptr,
                                                     nullptr, nullptr, nullptr,
                                                     BTOT, DMODEL, DMODEL);
}

// Round 6
// 409.007 us; speedup vs baseline: 3.3274x; 1.2125x over previous
//
#include <hip/hip_runtime.h>
#include <hip/hip_bf16.h>
#include <math.h>

// B=2, N=2048, D=1024, H=16, d=64, n_ctx=1024, P=256.
// bias -> split x/W to bf16 hi/lo -> QKV MFMA gemm -> swapped-QK MFMA flash attention
// (in-register P via key-permutation pi, defer-max, K/V double-buffer prefetch) -> out-proj.

#define NTOK 2048
#define DMODEL 1024
#define NHEAD 16
#define DHEAD 64
#define NCTX 1024
#define BTOT 4096

typedef __attribute__((ext_vector_type(8))) short  s8v;    // 8 bf16 bits (4 VGPR) MFMA operand
typedef __attribute__((ext_vector_type(4))) float  f4v;    // MFMA accumulator
typedef __attribute__((ext_vector_type(4))) ushort us4;
typedef __attribute__((ext_vector_type(8))) ushort us8;

__device__ __forceinline__ ushort f2bf(float x) {
    unsigned b = __float_as_uint(x);
    return (ushort)((b + 0x7FFFu + ((b >> 16) & 1u)) >> 16);
}
__device__ __forceinline__ float bf2f(ushort u) {
    return __uint_as_float(((unsigned)u) << 16);
}

// hi/lo split of a pair via packed cvt (v_cvt_pk_bf16_f32): 3 VALU/value
__device__ __forceinline__ void split_pair(float x0, float x1, unsigned& hu, unsigned& lu) {
    union { __hip_bfloat162 b; unsigned u; } H, L;
    H.b = __float22bfloat162_rn(make_float2(x0, x1));
    const float h0 = __bfloat162float(H.b.x);
    const float h1 = __bfloat162float(H.b.y);
    L.b = __float22bfloat162_rn(make_float2(x0 - h0, x1 - h1));
    hu = H.u; lu = L.u;
}

// global_load_lds width 16: linear LDS dest (wave-uniform base + lane*16), per-lane global src
#define GLDS16(gsrc, ldst) __builtin_amdgcn_global_load_lds(                              \
    (__attribute__((address_space(1))) unsigned int*)(gsrc),                              \
    (__attribute__((address_space(3))) unsigned int*)(ldst), 16, 0, 0)

// ---------------------------------------------------------------- bias kernel (unchanged)
__global__ __launch_bounds__(256)
void bias_kernel(const float* __restrict__ ctx_ppr, const float* __restrict__ ctx_delta,
                 const float* __restrict__ ctx_trust,
                 const float* __restrict__ alpha, const float* __restrict__ tscale,
                 const float* __restrict__ Wd1, const float* __restrict__ bd1,
                 const float* __restrict__ Wd2, const float* __restrict__ bd2,
                 float* __restrict__ gate_full, float* __restrict__ col_bias)
{
    const int i = blockIdx.x;
    const int t = threadIdx.x;
    if (i >= NCTX) {
        if (t == 0) { gate_full[i] = 1.0f; col_bias[i] = 0.0f; }
        return;
    }
    __shared__ float drow[256];
    __shared__ float red[256];
    drow[t] = ctx_delta[i * 256 + t];
    __syncthreads();

    float partial = 0.0f;
    #pragma unroll
    for (int jj = 0; jj < 2; jj++) {
        const int j = t + jj * 256;
        float s = bd1[j];
        const float4* wrow = (const float4*)&Wd1[j * 256];
        const float4* dr   = (const float4*)drow;
        #pragma unroll 8
        for (int p = 0; p < 64; p++) {
            float4 w = wrow[p], dd = dr[p];
            s += w.x * dd.x + w.y * dd.y + w.z * dd.z + w.w * dd.w;
        }
        float g = 0.5f * s * (1.0f + erff(s * 0.70710678118654752f));
        partial += g * Wd2[j];
    }
    red[t] = partial;
    __syncthreads();
    for (int off = 128; off > 0; off >>= 1) {
        if (t < off) red[t] += red[t + off];
        __syncthreads();
    }
    if (t == 0) {
        float ppr = fmaxf(ctx_ppr[i], 1e-8f);
        col_bias[i]  = alpha[0] * logf(ppr) + (red[0] + bd2[0]);
        gate_full[i] = 1.0f / (1.0f + __expf(-(tscale[0] * ctx_trust[i])));
    }
}

// ---------------------------------------------------------------- fp32 -> bf16 hi/lo split
__global__ __launch_bounds__(256)
void cvt_split(const float* __restrict__ in, ushort* __restrict__ hi,
               ushort* __restrict__ lo, int n4)
{
    for (int i = blockIdx.x * 256 + threadIdx.x; i < n4; i += gridDim.x * 256) {
        float4 v = ((const float4*)in)[i];
        us4 h, l; ushort hb;
        hb = f2bf(v.x); h[0] = hb; l[0] = f2bf(v.x - bf2f(hb));
        hb = f2bf(v.y); h[1] = hb; l[1] = f2bf(v.y - bf2f(hb));
        hb = f2bf(v.z); h[2] = hb; l[2] = f2bf(v.z - bf2f(hb));
        hb = f2bf(v.w); h[3] = hb; l[3] = f2bf(v.w - bf2f(hb));
        ((us4*)hi)[i] = h; ((us4*)lo)[i] = l;
    }
}

// ---------------------------------------------------------------- split-bf16 MFMA GEMM (unchanged)
template<int MT, int EPI>
__global__ __launch_bounds__(256)
void gemm_mfma(const ushort* __restrict__ Ah, const ushort* __restrict__ Al,
               const ushort* __restrict__ Bh, const ushort* __restrict__ Bl,
               const float* __restrict__ bias, float* __restrict__ C,
               ushort* __restrict__ qh, ushort* __restrict__ ql,
               ushort* __restrict__ kh, ushort* __restrict__ kl,
               ushort* __restrict__ vth, ushort* __restrict__ vtl,
               const float* __restrict__ gate_full, int M, int N, int K)
{
    constexpr int BM = MT * 32;
    __shared__ ushort AhS[BM * 32], AlS[BM * 32], BhS[4096], BlS[4096];

    const int t = threadIdx.x, lane = t & 63, wid = t >> 6;
    const int l15 = lane & 15, l4 = lane >> 4;
    const int wr = wid >> 1, wc = wid & 1;

    const int nwg = gridDim.x * gridDim.y;
    const int lin = blockIdx.y * gridDim.x + blockIdx.x;
    const int w   = (lin & 7) * (nwg >> 3) + (lin >> 3);
    const int bx  = w % gridDim.x, by = w / gridDim.x;
    const int m0 = by * BM, n0 = bx * 128;

    f4v acc[MT][4];
    #pragma unroll
    for (int mi = 0; mi < MT; mi++)
        #pragma unroll
        for (int nj = 0; nj < 4; nj++)
            #pragma unroll
            for (int r = 0; r < 4; r++) acc[mi][nj][r] = 0.0f;

    const int srow_l = lane >> 2;
    const int schunk = (lane & 3) ^ ((lane >> 2) & 3) ^ ((lane >> 4) & 3);
    const int rch = l4 ^ (l15 & 3) ^ ((l15 >> 2) & 3);

    const ushort* sA = (wid == 0) ? Ah : Al;
    const ushort* sB = (wid == 2) ? Bh : Bl;
    ushort* dA = (wid == 0) ? AhS : AlS;
    ushort* dB = (wid == 2) ? BhS : BlS;

    for (int k0 = 0; k0 < K; k0 += 32) {
        __syncthreads();
        if (wid < 2) {
            #pragma unroll
            for (int i = 0; i < BM / 16; i++) {
                const int row = i * 16 + srow_l;
                GLDS16(sA + (size_t)(m0 + row) * K + k0 + schunk * 8, dA + i * 512);
            }
        } else {
            #pragma unroll
            for (int i = 0; i < 8; i++) {
                const int row = i * 16 + srow_l;
                GLDS16(sB + (size_t)(n0 + row) * K + k0 + schunk * 8, dB + i * 512);
            }
        }
        __syncthreads();

        s8v afh[MT], afl[MT], bfh[4], bfl[4];
        #pragma unroll
        for (int mi = 0; mi < MT; mi++) {
            const int row = wr * (MT * 16) + mi * 16 + l15;
            afh[mi] = *(const s8v*)&AhS[row * 32 + rch * 8];
            afl[mi] = *(const s8v*)&AlS[row * 32 + rch * 8];
        }
        #pragma unroll
        for (int nj = 0; nj < 4; nj++) {
            const int row = wc * 64 + nj * 16 + l15;
            bfh[nj] = *(const s8v*)&BhS[row * 32 + rch * 8];
            bfl[nj] = *(const s8v*)&BlS[row * 32 + rch * 8];
        }
        #pragma unroll
        for (int mi = 0; mi < MT; mi++)
            #pragma unroll
            for (int nj = 0; nj < 4; nj++) {
                acc[mi][nj] = __builtin_amdgcn_mfma_f32_16x16x32_bf16(afh[mi], bfh[nj], acc[mi][nj], 0, 0, 0);
                acc[mi][nj] = __builtin_amdgcn_mfma_f32_16x16x32_bf16(afh[mi], bfl[nj], acc[mi][nj], 0, 0, 0);
                acc[mi][nj] = __builtin_amdgcn_mfma_f32_16x16x32_bf16(afl[mi], bfh[nj], acc[mi][nj], 0, 0, 0);
            }
    }

    if (EPI == 0) {
        #pragma unroll
        for (int mi = 0; mi < MT; mi++) {
            #pragma unroll
            for (int nj = 0; nj < 4; nj++) {
                const int n = n0 + wc * 64 + nj * 16 + l15;
                const float bn = bias[n];
                #pragma unroll
                for (int r = 0; r < 4; r++) {
                    const int m = m0 + wr * (MT * 16) + mi * 16 + l4 * 4 + r;
                    C[(size_t)m * N + n] = acc[mi][nj][r] + bn;
                }
            }
        }
    } else {
        const int sec = n0 >> 10;
        #pragma unroll
        for (int mi = 0; mi < MT; mi++) {
            const int mbase = m0 + wr * (MT * 16) + mi * 16 + l4 * 4;
            const int bb = mbase >> 11, tok0 = mbase & 2047;
            #pragma unroll
            for (int nj = 0; nj < 4; nj++) {
                const int n = n0 + wc * 64 + nj * 16 + l15;
                const float bn = bias[n];
                const int rem = n & 1023, h = rem >> 6, jd = rem & 63;
                if (sec == 2) {
                    us4 hv, lv;
                    #pragma unroll
                    for (int r = 0; r < 4; r++) {
                        const float o = (acc[mi][nj][r] + bn) * gate_full[tok0 + r];
                        const ushort hb = f2bf(o);
                        hv[r] = hb; lv[r] = f2bf(o - bf2f(hb));
                    }
                    const size_t vb = ((size_t)((bb << 4) + h) * 64 + jd) * NTOK + tok0;
                    *(us4*)&vth[vb] = hv;
                    *(us4*)&vtl[vb] = lv;
                } else {
                    ushort* dh = sec ? kh : qh;
                    ushort* dl = sec ? kl : ql;
                    #pragma unroll
                    for (int r = 0; r < 4; r++) {
                        const float o = acc[mi][nj][r] + bn;
                        const size_t idx = ((size_t)((bb << 4) + h) * NTOK + (tok0 + r)) * 64 + jd;
                        const ushort hb = f2bf(o);
                        dh[idx] = hb;
                        dl[idx] = f2bf(o - bf2f(hb));
                    }
                }
            }
        }
    }
}

// ---------------------------------------------------------------- swapped-QK MFMA flash attention
// Block = 4 waves, 128 q-rows (32/wave, 2 q-frags). KV tile 64, double-buffered.
// QK^T computed as mfma(K, Q) -> S^T: q is lane-local (col=l15), key = 16g+4*l4+r.
// P stays in registers: key-permutation pi(16g+4l4+r) = 8l4+32(g>>1)+4(g&1)+r maps each
// lane's held keys exactly onto its PV A-frag slots; V LDS stores pi-permuted key order
// (contraction is permutation-invariant when applied to both operands).
__global__ __launch_bounds__(256, 2)
void attn_mfma(const ushort* __restrict__ qh, const ushort* __restrict__ ql,
               const ushort* __restrict__ kh, const ushort* __restrict__ kl,
               const ushort* __restrict__ vth, const ushort* __restrict__ vtl,
               const float* __restrict__ col_bias,
               ushort* __restrict__ atth, ushort* __restrict__ attl)
{
    __shared__ ushort KS[2][2][4096];   // [buf][hi/lo][key 64][d 64] chunk-swizzled
    __shared__ ushort VS[2][2][4096];   // [buf][hi/lo][dh 64][kappa 64] pi-perm + swizzled
    __shared__ float  CBS[2][64];

    const int t = threadIdx.x, lane = t & 63, wid = t >> 6;
    const int lin = blockIdx.y * gridDim.x + blockIdx.x;   // 512 blocks
    const int w   = (lin & 7) * 64 + (lin >> 3);           // bijective XCD swizzle
    const int bh  = w >> 4, qt = w & 15;

    const size_t qkbase = (size_t)bh * (NTOK * DHEAD);
    const size_t vtbase = (size_t)bh * (DHEAD * NTOK);
    const int l15 = lane & 15, l4 = lane >> 4;
    const int q0 = qt * 128 + wid * 32;

    // Q fragments (B-operand): lane -> Q[q0+16qb+l15][32s+8l4+0..7]
    s8v qfh[2][2], qfl[2][2];
    #pragma unroll
    for (int qb = 0; qb < 2; qb++)
        #pragma unroll
        for (int s = 0; s < 2; s++) {
            const size_t off = qkbase + (size_t)(q0 + 16 * qb + l15) * 64 + 32 * s + 8 * l4;
            qfh[qb][s] = *(const s8v*)&qh[off];
            qfl[qb][s] = *(const s8v*)&ql[off];
        }

    f4v oacc[2][4];
    #pragma unroll
    for (int qb = 0; qb < 2; qb++)
        #pragma unroll
        for (int f = 0; f < 4; f++)
            #pragma unroll
            for (int r = 0; r < 4; r++) oacc[qb][f][r] = 0.0f;
    float mreg[2] = {-INFINITY, -INFINITY};
    float sreg[2] = {0.0f, 0.0f};

    // V reg-staging state (waves 2,3)
    us8 vreg[8];
    const int vj = lane & 7, vdh0 = lane >> 3;
    const int k0c  = 4 * (vj >> 2) + 2 * (vj & 1);        // kappa chunk (even)
    const int off0 = ((vj >> 1) & 1) * 8;                  // byte offset in chunk {0,8}

    // ---- staging helpers (inlined per call site)
    #define STAGE_K(nb, kt) do {                                                          \
        const ushort* sp_ = wid ? kl : kh;                                                \
        ushort* dp_ = &KS[nb][wid][0];                                                    \
        _Pragma("unroll")                                                                 \
        for (int i_ = 0; i_ < 8; i_++) {                                                  \
            const int row_ = i_ * 8 + (lane >> 3);                                        \
            const int sc_  = ((lane & 7) ^ (row_ & 7)) * 8;                               \
            GLDS16(sp_ + qkbase + (size_t)((kt) + row_) * 64 + sc_, dp_ + i_ * 512);      \
        }                                                                                 \
        if (wid == 0 && lane < 16) GLDS16(col_bias + (kt) + lane * 4, &CBS[nb][0]);       \
    } while (0)

    #define LOAD_V(kt) do {                                                               \
        const ushort* sp_ = (wid == 2) ? vth : vtl;                                       \
        _Pragma("unroll")                                                                 \
        for (int i_ = 0; i_ < 8; i_++)                                                    \
            vreg[i_] = *(const us8*)&sp_[vtbase + (size_t)(8 * i_ + vdh0) * NTOK + (kt) + 8 * vj]; \
    } while (0)

    #define STORE_V(nb) do {                                                              \
        char* dp_ = (char*)&VS[nb][wid - 2][0];                                           \
        _Pragma("unroll")                                                                 \
        for (int i_ = 0; i_ < 8; i_++) {                                                  \
            const int dh_ = 8 * i_ + vdh0;                                                \
            const int b0_ = dh_ * 128 + ((k0c ^ (dh_ & 7)) * 16) + off0;                  \
            const int b1_ = dh_ * 128 + (((k0c + 1) ^ (dh_ & 7)) * 16) + off0;            \
            us4 lo4_, hi4_;                                                               \
            lo4_[0] = vreg[i_][0]; lo4_[1] = vreg[i_][1];                                 \
            lo4_[2] = vreg[i_][2]; lo4_[3] = vreg[i_][3];                                 \
            hi4_[0] = vreg[i_][4]; hi4_[1] = vreg[i_][5];                                 \
            hi4_[2] = vreg[i_][6]; hi4_[3] = vreg[i_][7];                                 \
            *(us4*)(dp_ + b0_) = lo4_;                                                    \
            *(us4*)(dp_ + b1_) = hi4_;                                                    \
        }                                                                                 \
    } while (0)

    // prologue: stage tile 0
    if (wid < 2) STAGE_K(0, 0); else { LOAD_V(0); STORE_V(0); }
    __syncthreads();

    int cur = 0;
    for (int kt = 0; kt < 32; kt++) {
        const int nxt = cur ^ 1;
        if (kt < 31) { if (wid < 2) STAGE_K(nxt, (kt + 1) * 64); else LOAD_V((kt + 1) * 64); }

        // ---- QK^T (3-term): sa[qb][g], row=key=16g+4l4+r, col=q=l15
        f4v sa[2][4];
        #pragma unroll
        for (int qb = 0; qb < 2; qb++)
            #pragma unroll
            for (int g = 0; g < 4; g++)
                #pragma unroll
                for (int r = 0; r < 4; r++) sa[qb][g][r] = 0.0f;
        #pragma unroll
        for (int s = 0; s < 2; s++) {
            #pragma unroll
            for (int g = 0; g < 4; g++) {
                const int row = 16 * g + l15;
                const int idx = row * 64 + (((4 * s + l4) ^ (l15 & 7))) * 8;
                s8v kfh = *(const s8v*)&KS[cur][0][idx];
                s8v kfl = *(const s8v*)&KS[cur][1][idx];
                #pragma unroll
                for (int qb = 0; qb < 2; qb++) {
                    sa[qb][g] = __builtin_amdgcn_mfma_f32_16x16x32_bf16(kfh, qfh[qb][s], sa[qb][g], 0, 0, 0);
                    sa[qb][g] = __builtin_amdgcn_mfma_f32_16x16x32_bf16(kfl, qfh[qb][s], sa[qb][g], 0, 0, 0);
                    sa[qb][g] = __builtin_amdgcn_mfma_f32_16x16x32_bf16(kfh, qfl[qb][s], sa[qb][g], 0, 0, 0);
                }
            }
        }

        // ---- logits + defer-max online softmax (key dim is in-lane: NO shfl steady-state)
        float cbv[4][4];
        #pragma unroll
        for (int g = 0; g < 4; g++)
            #pragma unroll
            for (int r = 0; r < 4; r++) cbv[g][r] = CBS[cur][16 * g + 4 * l4 + r];

        float sv[2][4][4], smax[2];
        #pragma unroll
        for (int qb = 0; qb < 2; qb++) {
            float m = -INFINITY;
            #pragma unroll
            for (int g = 0; g < 4; g++)
                #pragma unroll
                for (int r = 0; r < 4; r++) {
                    const float x = sa[qb][g][r] * 0.125f + cbv[g][r];
                    sv[qb][g][r] = x;
                    m = fmaxf(m, x);
                }
            smax[qb] = m;
        }
        const int need = (smax[0] > mreg[0] + 8.0f) || (smax[1] > mreg[1] + 8.0f);
        if (__any(need)) {
            #pragma unroll
            for (int qb = 0; qb < 2; qb++) {
                float mx = smax[qb];
                mx = fmaxf(mx, __shfl_xor(mx, 16));
                mx = fmaxf(mx, __shfl_xor(mx, 32));
                const float mnew = fmaxf(mreg[qb], mx);
                const float fs = __expf(mreg[qb] - mnew);   // first tile: exp(-inf)=0
                mreg[qb] = mnew;
                sreg[qb] *= fs;
                float fq[4];
                #pragma unroll
                for (int r = 0; r < 4; r++) fq[r] = __shfl(fs, 4 * l4 + r);
                #pragma unroll
                for (int f = 0; f < 4; f++)
                    #pragma unroll
                    for (int r = 0; r < 4; r++) oacc[qb][f][r] *= fq[r];
            }
        }

        // ---- p = exp(s - m) and pack into PV A-frags via pi (pure registers)
        union S8 { s8v v; unsigned u[4]; };
        S8 pa_h[2][2], pa_l[2][2];
        #pragma unroll
        for (int qb = 0; qb < 2; qb++) {
            float pv[4][4];
            float acc_s = 0.0f;
            #pragma unroll
            for (int g = 0; g < 4; g++)
                #pragma unroll
                for (int r = 0; r < 4; r++) {
                    const float p = __expf(sv[qb][g][r] - mreg[qb]);
                    pv[g][r] = p;
                    acc_s += p;
                }
            sreg[qb] += acc_s;
            #pragma unroll
            for (int s = 0; s < 2; s++)
                #pragma unroll
                for (int a = 0; a < 2; a++) {
                    const int g = 2 * s + a;
                    split_pair(pv[g][0], pv[g][1], pa_h[qb][s].u[2 * a],     pa_l[qb][s].u[2 * a]);
                    split_pair(pv[g][2], pv[g][3], pa_h[qb][s].u[2 * a + 1], pa_l[qb][s].u[2 * a + 1]);
                }
        }

        // ---- PV (3-term): O[q][dh] += P pi-slots x V pi-layout
        #pragma unroll
        for (int s = 0; s < 2; s++) {
            #pragma unroll
            for (int f = 0; f < 4; f++) {
                const int row = 16 * f + l15;
                const int idx = row * 64 + (((4 * s + l4) ^ (l15 & 7))) * 8;
                s8v vfh = *(const s8v*)&VS[cur][0][idx];
                s8v vfl = *(const s8v*)&VS[cur][1][idx];
                #pragma unroll
                for (int qb = 0; qb < 2; qb++) {
                    oacc[qb][f] = __builtin_amdgcn_mfma_f32_16x16x32_bf16(pa_h[qb][s].v, vfh, oacc[qb][f], 0, 0, 0);
                    oacc[qb][f] = __builtin_amdgcn_mfma_f32_16x16x32_bf16(pa_h[qb][s].v, vfl, oacc[qb][f], 0, 0, 0);
                    oacc[qb][f] = __builtin_amdgcn_mfma_f32_16x16x32_bf16(pa_l[qb][s].v, vfh, oacc[qb][f], 0, 0, 0);
                }
            }
        }

        if (kt < 31 && wid >= 2) STORE_V(nxt);
        __syncthreads();
        cur = nxt;
    }

    // ---- epilogue: final sum reduce across l4 groups, normalize, emit att hi/lo
    const int b = bh >> 4, h = bh & 15;
    #pragma unroll
    for (int qb = 0; qb < 2; qb++) {
        float ts = sreg[qb];
        ts += __shfl_xor(ts, 16);
        ts += __shfl_xor(ts, 32);
        const float inv = 1.0f / ts;
        float invq[4];
        #pragma unroll
        for (int r = 0; r < 4; r++) invq[r] = __shfl(inv, 4 * l4 + r);
        #pragma unroll
        for (int r = 0; r < 4; r++) {
            const int q = q0 + 16 * qb + 4 * l4 + r;
            const size_t o = ((size_t)(b * NTOK + q)) * DMODEL + h * DHEAD + l15;
            #pragma unroll
            for (int f = 0; f < 4; f++) {
                const float v = oacc[qb][f][r] * invq[r];
                const ushort hb = f2bf(v);
                atth[o + 16 * f] = hb;
                attl[o + 16 * f] = f2bf(v - bf2f(hb));
            }
        }
    }
    #undef STAGE_K
    #undef LOAD_V
    #undef STORE_V
}

// ---------------------------------------------------------------- launch
extern "C" void kernel_launch(void* const* d_in, const int* in_sizes, int n_in,
                              void* d_out, int out_size, void* d_ws, size_t ws_size,
                              hipStream_t stream)
{
    const float* x         = (const float*)d_in[0];
    const float* ctx_ppr   = (const float*)d_in[2];
    const float* ctx_delta = (const float*)d_in[3];
    const float* ctx_trust = (const float*)d_in[4];
    const float* W_in      = (const float*)d_in[5];
    const float* b_in      = (const float*)d_in[6];
    const float* W_out     = (const float*)d_in[7];
    const float* b_out     = (const float*)d_in[8];
    const float* alpha     = (const float*)d_in[9];
    const float* tscale    = (const float*)d_in[10];
    const float* Wd1       = (const float*)d_in[11];
    const float* bd1       = (const float*)d_in[12];
    const float* Wd2       = (const float*)d_in[13];
    const float* bd2       = (const float*)d_in[14];
    float* out = (float*)d_out;

    float* ws = (float*)d_ws;
    float* gate_full = ws;                          // 2048 f
    float* col_bias  = ws + 2048;                   // 2048 f
    ushort* u = (ushort*)(ws + 4096);
    ushort* xh  = u;  u += 4194304;                 // aliased: atth after attn
    ushort* xl  = u;  u += 4194304;                 // aliased: attl
    ushort* wih = u;  u += 3145728;
    ushort* wil = u;  u += 3145728;
    ushort* woh = u;  u += 1048576;
    ushort* wol = u;  u += 1048576;
    ushort* qh  = u;  u += 4194304;
    ushort* ql  = u;  u += 4194304;
    ushort* kh  = u;  u += 4194304;
    ushort* kl  = u;  u += 4194304;
    ushort* vth = u;  u += 4194304;
    ushort* vtl = u;  u += 4194304;                 // total ~84 MB

    bias_kernel<<<NTOK, 256, 0, stream>>>(ctx_ppr, ctx_delta, ctx_trust, alpha, tscale,
                                          Wd1, bd1, Wd2, bd2, gate_full, col_bias);
    cvt_split<<<1024, 256, 0, stream>>>(x,     xh,  xl,  1048576);
    cvt_split<<<768,  256, 0, stream>>>(W_in,  wih, wil, 786432);
    cvt_split<<<256,  256, 0, stream>>>(W_out, woh, wol, 262144);

    gemm_mfma<4, 1><<<dim3(24, 32), 256, 0, stream>>>(xh, xl, wih, wil, b_in, nullptr,
                                                      qh, ql, kh, kl, vth, vtl, gate_full,
                                                      BTOT, 3 * DMODEL, DMODEL);
    attn_mfma<<<dim3(16, 32), 256, 0, stream>>>(qh, ql, kh, kl, vth, vtl, col_bias,
                                                xh, xl);   // att hi/lo reuses x buffers
    gemm_mfma<2, 0><<<dim3(8, 64), 256, 0, stream>>>(xh, xl, woh, wol, b_out, out,
                                                     nullptr, nullptr, nullptr, nullptr,
                                                     nullptr, nullptr, nullptr,
                                                     BTOT, DMODEL, DMODEL);
}

// Round 7
// 352.732 us; speedup vs baseline: 3.8582x; 1.1595x over previous
//
#include <hip/hip_runtime.h>
#include <hip/hip_bf16.h>
#include <hip/hip_fp16.h>
#include <math.h>

// B=2, N=2048, D=1024, H=16, d=64, n_ctx=1024, P=256.
// bias -> cvt (x,W_in -> fp16; W_out -> bf16 hi/lo) -> fp16 QKV MFMA gemm
// -> fp16 swapped-QK MFMA flash attention (in-register P, defer-max, dbuf prefetch)
// -> split-bf16 out-proj MFMA gemm (precision hedge on the final output path).

#define NTOK 2048
#define DMODEL 1024
#define NHEAD 16
#define DHEAD 64
#define NCTX 1024
#define BTOT 4096

typedef __attribute__((ext_vector_type(8))) short    s8v;   // 8 bf16 bits (4 VGPR)
typedef __attribute__((ext_vector_type(8))) _Float16 h8v;   // 8 fp16 (4 VGPR)
typedef __attribute__((ext_vector_type(4))) float    f4v;
typedef __attribute__((ext_vector_type(4))) ushort   us4;
typedef __attribute__((ext_vector_type(8))) ushort   us8;

__device__ __forceinline__ ushort f2bf(float x) {
    unsigned b = __float_as_uint(x);
    return (ushort)((b + 0x7FFFu + ((b >> 16) & 1u)) >> 16);
}
__device__ __forceinline__ float bf2f(ushort u) {
    return __uint_as_float(((unsigned)u) << 16);
}
__device__ __forceinline__ ushort f2h(float x) {
    return __half_as_ushort(__float2half_rn(x));
}

// global_load_lds width 16: linear LDS dest (wave-uniform base + lane*16), per-lane global src
#define GLDS16(gsrc, ldst) __builtin_amdgcn_global_load_lds(                              \
    (__attribute__((address_space(1))) unsigned int*)(gsrc),                              \
    (__attribute__((address_space(3))) unsigned int*)(ldst), 16, 0, 0)

// ---------------------------------------------------------------- bias kernel (unchanged)
__global__ __launch_bounds__(256)
void bias_kernel(const float* __restrict__ ctx_ppr, const float* __restrict__ ctx_delta,
                 const float* __restrict__ ctx_trust,
                 const float* __restrict__ alpha, const float* __restrict__ tscale,
                 const float* __restrict__ Wd1, const float* __restrict__ bd1,
                 const float* __restrict__ Wd2, const float* __restrict__ bd2,
                 float* __restrict__ gate_full, float* __restrict__ col_bias)
{
    const int i = blockIdx.x;
    const int t = threadIdx.x;
    if (i >= NCTX) {
        if (t == 0) { gate_full[i] = 1.0f; col_bias[i] = 0.0f; }
        return;
    }
    __shared__ float drow[256];
    __shared__ float red[256];
    drow[t] = ctx_delta[i * 256 + t];
    __syncthreads();

    float partial = 0.0f;
    #pragma unroll
    for (int jj = 0; jj < 2; jj++) {
        const int j = t + jj * 256;
        float s = bd1[j];
        const float4* wrow = (const float4*)&Wd1[j * 256];
        const float4* dr   = (const float4*)drow;
        #pragma unroll 8
        for (int p = 0; p < 64; p++) {
            float4 w = wrow[p], dd = dr[p];
            s += w.x * dd.x + w.y * dd.y + w.z * dd.z + w.w * dd.w;
        }
        float g = 0.5f * s * (1.0f + erff(s * 0.70710678118654752f));
        partial += g * Wd2[j];
    }
    red[t] = partial;
    __syncthreads();
    for (int off = 128; off > 0; off >>= 1) {
        if (t < off) red[t] += red[t + off];
        __syncthreads();
    }
    if (t == 0) {
        float ppr = fmaxf(ctx_ppr[i], 1e-8f);
        col_bias[i]  = alpha[0] * logf(ppr) + (red[0] + bd2[0]);
        gate_full[i] = 1.0f / (1.0f + __expf(-(tscale[0] * ctx_trust[i])));
    }
}

// ---------------------------------------------------------------- converts
__global__ __launch_bounds__(256)
void cvt_split(const float* __restrict__ in, ushort* __restrict__ hi,
               ushort* __restrict__ lo, int n4)
{
    for (int i = blockIdx.x * 256 + threadIdx.x; i < n4; i += gridDim.x * 256) {
        float4 v = ((const float4*)in)[i];
        us4 h, l; ushort hb;
        hb = f2bf(v.x); h[0] = hb; l[0] = f2bf(v.x - bf2f(hb));
        hb = f2bf(v.y); h[1] = hb; l[1] = f2bf(v.y - bf2f(hb));
        hb = f2bf(v.z); h[2] = hb; l[2] = f2bf(v.z - bf2f(hb));
        hb = f2bf(v.w); h[3] = hb; l[3] = f2bf(v.w - bf2f(hb));
        ((us4*)hi)[i] = h; ((us4*)lo)[i] = l;
    }
}

__global__ __launch_bounds__(256)
void cvt_f16(const float* __restrict__ in, ushort* __restrict__ out16, int n4)
{
    for (int i = blockIdx.x * 256 + threadIdx.x; i < n4; i += gridDim.x * 256) {
        float4 v = ((const float4*)in)[i];
        us4 h;
        h[0] = f2h(v.x); h[1] = f2h(v.y); h[2] = f2h(v.z); h[3] = f2h(v.w);
        ((us4*)out16)[i] = h;
    }
}

// ---------------------------------------------------------------- fp16 MFMA GEMM (QKV)
// C = A @ B^T + bias. A [M][K] fp16, B [N][K] fp16, fp32 accum, single-term.
// 128x128 tile, BK=32, 4 waves 2x2, 4x4 16x16x32 frags per wave.
// Epilogue scatters q/k fp16 [bh][tok][64] and V^T fp16 [bh][64][tok], gated.
__global__ __launch_bounds__(256, 3)
void gemm_f16(const ushort* __restrict__ Af, const ushort* __restrict__ Bf,
              const float* __restrict__ bias,
              ushort* __restrict__ qf, ushort* __restrict__ kf,
              ushort* __restrict__ vtf,
              const float* __restrict__ gate_full, int M, int N, int K)
{
    __shared__ ushort AS[4096], BS[4096];     // 128 rows x 32 cols fp16, chunk-swizzled

    const int t = threadIdx.x, lane = t & 63, wid = t >> 6;
    const int l15 = lane & 15, l4 = lane >> 4;
    const int wr = wid >> 1, wc = wid & 1;

    const int nwg = gridDim.x * gridDim.y;
    const int lin = blockIdx.y * gridDim.x + blockIdx.x;
    const int w   = (lin & 7) * (nwg >> 3) + (lin >> 3);
    const int bx  = w % gridDim.x, by = w / gridDim.x;
    const int m0 = by * 128, n0 = bx * 128;

    f4v acc[4][4];
    #pragma unroll
    for (int mi = 0; mi < 4; mi++)
        #pragma unroll
        for (int nj = 0; nj < 4; nj++)
            #pragma unroll
            for (int r = 0; r < 4; r++) acc[mi][nj][r] = 0.0f;

    const int srow_l = lane >> 2;
    const int schunk = (lane & 3) ^ ((lane >> 2) & 3) ^ ((lane >> 4) & 3);
    const int rch = l4 ^ (l15 & 3) ^ ((l15 >> 2) & 3);

    const ushort* sp = (wid < 2) ? Af : Bf;
    ushort* dp = (wid < 2) ? AS : BS;
    const int wofs = (wid & 1) * 64;          // row half within the operand
    const int base0 = (wid < 2) ? m0 : n0;

    for (int k0 = 0; k0 < K; k0 += 32) {
        __syncthreads();
        #pragma unroll
        for (int i = 0; i < 4; i++) {
            const int row = wofs + i * 16 + srow_l;
            GLDS16(sp + (size_t)(base0 + row) * K + k0 + schunk * 8,
                   dp + ((wid & 1) * 4 + i) * 512);
        }
        __syncthreads();

        h8v af[4], bf[4];
        #pragma unroll
        for (int mi = 0; mi < 4; mi++) {
            const int row = wr * 64 + mi * 16 + l15;
            af[mi] = *(const h8v*)&AS[row * 32 + rch * 8];
        }
        #pragma unroll
        for (int nj = 0; nj < 4; nj++) {
            const int row = wc * 64 + nj * 16 + l15;
            bf[nj] = *(const h8v*)&BS[row * 32 + rch * 8];
        }
        #pragma unroll
        for (int mi = 0; mi < 4; mi++)
            #pragma unroll
            for (int nj = 0; nj < 4; nj++)
                acc[mi][nj] = __builtin_amdgcn_mfma_f32_16x16x32_f16(af[mi], bf[nj], acc[mi][nj], 0, 0, 0);
    }

    const int sec = n0 >> 10;                 // 0=q 1=k 2=v (uniform per block)
    #pragma unroll
    for (int mi = 0; mi < 4; mi++) {
        const int mbase = m0 + wr * 64 + mi * 16 + l4 * 4;
        const int bb = mbase >> 11, tok0 = mbase & 2047;
        #pragma unroll
        for (int nj = 0; nj < 4; nj++) {
            const int n = n0 + wc * 64 + nj * 16 + l15;
            const float bn = bias[n];
            const int rem = n & 1023, h = rem >> 6, jd = rem & 63;
            if (sec == 2) {
                us4 hv;
                #pragma unroll
                for (int r = 0; r < 4; r++)
                    hv[r] = f2h((acc[mi][nj][r] + bn) * gate_full[tok0 + r]);
                const size_t vb = ((size_t)((bb << 4) + h) * 64 + jd) * NTOK + tok0;
                *(us4*)&vtf[vb] = hv;
            } else {
                ushort* dst = sec ? kf : qf;
                #pragma unroll
                for (int r = 0; r < 4; r++) {
                    const size_t idx = ((size_t)((bb << 4) + h) * NTOK + (tok0 + r)) * 64 + jd;
                    dst[idx] = f2h(acc[mi][nj][r] + bn);
                }
            }
        }
    }
}

// ---------------------------------------------------------------- split-bf16 MFMA GEMM (out-proj)
template<int MT, int EPI>
__global__ __launch_bounds__(256)
void gemm_mfma(const ushort* __restrict__ Ah, const ushort* __restrict__ Al,
               const ushort* __restrict__ Bh, const ushort* __restrict__ Bl,
               const float* __restrict__ bias, float* __restrict__ C,
               const float* __restrict__ gate_full, int M, int N, int K)
{
    constexpr int BM = MT * 32;
    __shared__ ushort AhS[BM * 32], AlS[BM * 32], BhS[4096], BlS[4096];

    const int t = threadIdx.x, lane = t & 63, wid = t >> 6;
    const int l15 = lane & 15, l4 = lane >> 4;
    const int wr = wid >> 1, wc = wid & 1;

    const int nwg = gridDim.x * gridDim.y;
    const int lin = blockIdx.y * gridDim.x + blockIdx.x;
    const int w   = (lin & 7) * (nwg >> 3) + (lin >> 3);
    const int bx  = w % gridDim.x, by = w / gridDim.x;
    const int m0 = by * BM, n0 = bx * 128;

    f4v acc[MT][4];
    #pragma unroll
    for (int mi = 0; mi < MT; mi++)
        #pragma unroll
        for (int nj = 0; nj < 4; nj++)
            #pragma unroll
            for (int r = 0; r < 4; r++) acc[mi][nj][r] = 0.0f;

    const int srow_l = lane >> 2;
    const int schunk = (lane & 3) ^ ((lane >> 2) & 3) ^ ((lane >> 4) & 3);
    const int rch = l4 ^ (l15 & 3) ^ ((l15 >> 2) & 3);

    const ushort* sA = (wid == 0) ? Ah : Al;
    const ushort* sB = (wid == 2) ? Bh : Bl;
    ushort* dA = (wid == 0) ? AhS : AlS;
    ushort* dB = (wid == 2) ? BhS : BlS;

    for (int k0 = 0; k0 < K; k0 += 32) {
        __syncthreads();
        if (wid < 2) {
            #pragma unroll
            for (int i = 0; i < BM / 16; i++) {
                const int row = i * 16 + srow_l;
                GLDS16(sA + (size_t)(m0 + row) * K + k0 + schunk * 8, dA + i * 512);
            }
        } else {
            #pragma unroll
            for (int i = 0; i < 8; i++) {
                const int row = i * 16 + srow_l;
                GLDS16(sB + (size_t)(n0 + row) * K + k0 + schunk * 8, dB + i * 512);
            }
        }
        __syncthreads();

        s8v afh[MT], afl[MT], bfh[4], bfl[4];
        #pragma unroll
        for (int mi = 0; mi < MT; mi++) {
            const int row = wr * (MT * 16) + mi * 16 + l15;
            afh[mi] = *(const s8v*)&AhS[row * 32 + rch * 8];
            afl[mi] = *(const s8v*)&AlS[row * 32 + rch * 8];
        }
        #pragma unroll
        for (int nj = 0; nj < 4; nj++) {
            const int row = wc * 64 + nj * 16 + l15;
            bfh[nj] = *(const s8v*)&BhS[row * 32 + rch * 8];
            bfl[nj] = *(const s8v*)&BlS[row * 32 + rch * 8];
        }
        #pragma unroll
        for (int mi = 0; mi < MT; mi++)
            #pragma unroll
            for (int nj = 0; nj < 4; nj++) {
                acc[mi][nj] = __builtin_amdgcn_mfma_f32_16x16x32_bf16(afh[mi], bfh[nj], acc[mi][nj], 0, 0, 0);
                acc[mi][nj] = __builtin_amdgcn_mfma_f32_16x16x32_bf16(afh[mi], bfl[nj], acc[mi][nj], 0, 0, 0);
                acc[mi][nj] = __builtin_amdgcn_mfma_f32_16x16x32_bf16(afl[mi], bfh[nj], acc[mi][nj], 0, 0, 0);
            }
    }

    #pragma unroll
    for (int mi = 0; mi < MT; mi++) {
        #pragma unroll
        for (int nj = 0; nj < 4; nj++) {
            const int n = n0 + wc * 64 + nj * 16 + l15;
            const float bn = bias[n];
            #pragma unroll
            for (int r = 0; r < 4; r++) {
                const int m = m0 + wr * (MT * 16) + mi * 16 + l4 * 4 + r;
                C[(size_t)m * N + n] = acc[mi][nj][r] + bn;
            }
        }
    }
}

// ---------------------------------------------------------------- fp16 swapped-QK flash attention
// Block = 4 waves, 128 q-rows (32/wave). KV tile 64, double-buffered (33 KB LDS -> 4 blocks/CU).
// QK^T as mfma(K, Q) -> q lane-local; P in registers via key-permutation pi
// pi(16g+4l4+r) = 8l4+32(g>>1)+4(g&1)+r; V LDS stores pi-permuted key order.
__global__ __launch_bounds__(256, 4)
void attn_f16(const ushort* __restrict__ qfp, const ushort* __restrict__ kfp,
              const ushort* __restrict__ vtf, const float* __restrict__ col_bias,
              ushort* __restrict__ atth, ushort* __restrict__ attl)
{
    __shared__ ushort KS[2][4096];   // [buf][key 64][d 64] chunk-swizzled
    __shared__ ushort VS[2][4096];   // [buf][dh 64][kappa 64] pi-perm + swizzled
    __shared__ float  CBS[2][64];

    const int t = threadIdx.x, lane = t & 63, wid = t >> 6;
    const int lin = blockIdx.y * gridDim.x + blockIdx.x;   // 512 blocks
    const int w   = (lin & 7) * 64 + (lin >> 3);           // bijective XCD swizzle
    const int bh  = w >> 4, qt = w & 15;

    const size_t qkbase = (size_t)bh * (NTOK * DHEAD);
    const size_t vtbase = (size_t)bh * (DHEAD * NTOK);
    const int l15 = lane & 15, l4 = lane >> 4;
    const int q0 = qt * 128 + wid * 32;

    // Q fragments (B-operand): lane -> Q[q0+16qb+l15][32s+8l4+0..7]
    h8v qf[2][2];
    #pragma unroll
    for (int qb = 0; qb < 2; qb++)
        #pragma unroll
        for (int s = 0; s < 2; s++)
            qf[qb][s] = *(const h8v*)&qfp[qkbase + (size_t)(q0 + 16 * qb + l15) * 64 + 32 * s + 8 * l4];

    f4v oacc[2][4];
    #pragma unroll
    for (int qb = 0; qb < 2; qb++)
        #pragma unroll
        for (int f = 0; f < 4; f++)
            #pragma unroll
            for (int r = 0; r < 4; r++) oacc[qb][f][r] = 0.0f;
    float mreg[2] = {-INFINITY, -INFINITY};
    float sreg[2] = {0.0f, 0.0f};

    // V reg-staging (waves 2,3: 32 dh rows each)
    us8 vreg[4];
    const int vj = lane & 7, vdh0 = lane >> 3;
    const int k0c  = 4 * (vj >> 2) + 2 * (vj & 1);
    const int off0 = ((vj >> 1) & 1) * 8;

    // K staging (waves 0,1: 32 key rows each; wave 0 also stages col_bias)
    #define STAGE_K(nb, kt) do {                                                          \
        _Pragma("unroll")                                                                 \
        for (int i_ = 0; i_ < 4; i_++) {                                                  \
            const int row_ = wid * 32 + i_ * 8 + (lane >> 3);                             \
            const int sc_  = ((lane & 7) ^ (row_ & 7)) * 8;                               \
            GLDS16(kfp + qkbase + (size_t)((kt) + row_) * 64 + sc_,                       \
                   &KS[nb][0] + (wid * 4 + i_) * 512);                                    \
        }                                                                                 \
        if (wid == 0 && lane < 16) GLDS16(col_bias + (kt) + lane * 4, &CBS[nb][0]);       \
    } while (0)

    #define LOAD_V(kt) do {                                                               \
        _Pragma("unroll")                                                                 \
        for (int i_ = 0; i_ < 4; i_++) {                                                  \
            const int dh_ = (wid - 2) * 32 + 8 * i_ + vdh0;                               \
            vreg[i_] = *(const us8*)&vtf[vtbase + (size_t)dh_ * NTOK + (kt) + 8 * vj];    \
        }                                                                                 \
    } while (0)

    #define STORE_V(nb) do {                                                              \
        char* dp_ = (char*)&VS[nb][0];                                                    \
        _Pragma("unroll")                                                                 \
        for (int i_ = 0; i_ < 4; i_++) {                                                  \
            const int dh_ = (wid - 2) * 32 + 8 * i_ + vdh0;                               \
            const int b0_ = dh_ * 128 + ((k0c ^ (dh_ & 7)) * 16) + off0;                  \
            const int b1_ = dh_ * 128 + (((k0c + 1) ^ (dh_ & 7)) * 16) + off0;            \
            us4 lo4_, hi4_;                                                               \
            lo4_[0] = vreg[i_][0]; lo4_[1] = vreg[i_][1];                                 \
            lo4_[2] = vreg[i_][2]; lo4_[3] = vreg[i_][3];                                 \
            hi4_[0] = vreg[i_][4]; hi4_[1] = vreg[i_][5];                                 \
            hi4_[2] = vreg[i_][6]; hi4_[3] = vreg[i_][7];                                 \
            *(us4*)(dp_ + b0_) = lo4_;                                                    \
            *(us4*)(dp_ + b1_) = hi4_;                                                    \
        }                                                                                 \
    } while (0)

    if (wid < 2) STAGE_K(0, 0); else { LOAD_V(0); STORE_V(0); }
    __syncthreads();

    int cur = 0;
    for (int kt = 0; kt < 32; kt++) {
        const int nxt = cur ^ 1;
        if (kt < 31) { if (wid < 2) STAGE_K(nxt, (kt + 1) * 64); else LOAD_V((kt + 1) * 64); }

        // ---- QK^T: sa[qb][g], row=key=16g+4l4+r, col=q=l15
        f4v sa[2][4];
        #pragma unroll
        for (int qb = 0; qb < 2; qb++)
            #pragma unroll
            for (int g = 0; g < 4; g++)
                #pragma unroll
                for (int r = 0; r < 4; r++) sa[qb][g][r] = 0.0f;
        __builtin_amdgcn_s_setprio(1);
        #pragma unroll
        for (int s = 0; s < 2; s++) {
            #pragma unroll
            for (int g = 0; g < 4; g++) {
                const int row = 16 * g + l15;
                const int idx = row * 64 + (((4 * s + l4) ^ (l15 & 7))) * 8;
                h8v kfr = *(const h8v*)&KS[cur][idx];
                #pragma unroll
                for (int qb = 0; qb < 2; qb++)
                    sa[qb][g] = __builtin_amdgcn_mfma_f32_16x16x32_f16(kfr, qf[qb][s], sa[qb][g], 0, 0, 0);
            }
        }
        __builtin_amdgcn_s_setprio(0);

        // ---- logits + defer-max online softmax (key dim in-lane: no shfl steady-state)
        float cbv[4][4];
        #pragma unroll
        for (int g = 0; g < 4; g++)
            #pragma unroll
            for (int r = 0; r < 4; r++) cbv[g][r] = CBS[cur][16 * g + 4 * l4 + r];

        float sv[2][4][4], smax[2];
        #pragma unroll
        for (int qb = 0; qb < 2; qb++) {
            float m = -INFINITY;
            #pragma unroll
            for (int g = 0; g < 4; g++)
                #pragma unroll
                for (int r = 0; r < 4; r++) {
                    const float x = sa[qb][g][r] * 0.125f + cbv[g][r];
                    sv[qb][g][r] = x;
                    m = fmaxf(m, x);
                }
            smax[qb] = m;
        }
        const int need = (smax[0] > mreg[0] + 8.0f) || (smax[1] > mreg[1] + 8.0f);
        if (__any(need)) {
            #pragma unroll
            for (int qb = 0; qb < 2; qb++) {
                float mx = smax[qb];
                mx = fmaxf(mx, __shfl_xor(mx, 16));
                mx = fmaxf(mx, __shfl_xor(mx, 32));
                const float mnew = fmaxf(mreg[qb], mx);
                const float fs = __expf(mreg[qb] - mnew);   // first tile: exp(-inf)=0
                mreg[qb] = mnew;
                sreg[qb] *= fs;
                float fq[4];
                #pragma unroll
                for (int r = 0; r < 4; r++) fq[r] = __shfl(fs, 4 * l4 + r);
                #pragma unroll
                for (int f = 0; f < 4; f++)
                    #pragma unroll
                    for (int r = 0; r < 4; r++) oacc[qb][f][r] *= fq[r];
            }
        }

        // ---- p = exp(s - m), pack to fp16 PV A-frags via pi (pure registers)
        union H8 { h8v v; __half2 h2[4]; };
        H8 pa[2][2];
        #pragma unroll
        for (int qb = 0; qb < 2; qb++) {
            float pv[4][4];
            float acc_s = 0.0f;
            #pragma unroll
            for (int g = 0; g < 4; g++)
                #pragma unroll
                for (int r = 0; r < 4; r++) {
                    const float p = __expf(sv[qb][g][r] - mreg[qb]);  // p <= e^8, fits fp16
                    pv[g][r] = p;
                    acc_s += p;
                }
            sreg[qb] += acc_s;
            #pragma unroll
            for (int s = 0; s < 2; s++)
                #pragma unroll
                for (int a = 0; a < 2; a++) {
                    const int g = 2 * s + a;
                    pa[qb][s].h2[2 * a]     = __float22half2_rn(make_float2(pv[g][0], pv[g][1]));
                    pa[qb][s].h2[2 * a + 1] = __float22half2_rn(make_float2(pv[g][2], pv[g][3]));
                }
        }

        // ---- PV: O[q][dh] += P pi-slots x V pi-layout
        __builtin_amdgcn_s_setprio(1);
        #pragma unroll
        for (int s = 0; s < 2; s++) {
            #pragma unroll
            for (int f = 0; f < 4; f++) {
                const int row = 16 * f + l15;
                const int idx = row * 64 + (((4 * s + l4) ^ (l15 & 7))) * 8;
                h8v vfr = *(const h8v*)&VS[cur][idx];
                #pragma unroll
                for (int qb = 0; qb < 2; qb++)
                    oacc[qb][f] = __builtin_amdgcn_mfma_f32_16x16x32_f16(pa[qb][s].v, vfr, oacc[qb][f], 0, 0, 0);
            }
        }
        __builtin_amdgcn_s_setprio(0);

        if (kt < 31 && wid >= 2) STORE_V(nxt);
        __syncthreads();
        cur = nxt;
    }

    // ---- epilogue: reduce l across l4 groups, normalize, emit att hi/lo bf16
    const int b = bh >> 4, h = bh & 15;
    #pragma unroll
    for (int qb = 0; qb < 2; qb++) {
        float ts = sreg[qb];
        ts += __shfl_xor(ts, 16);
        ts += __shfl_xor(ts, 32);
        const float inv = 1.0f / ts;
        float invq[4];
        #pragma unroll
        for (int r = 0; r < 4; r++) invq[r] = __shfl(inv, 4 * l4 + r);
        #pragma unroll
        for (int r = 0; r < 4; r++) {
            const int q = q0 + 16 * qb + 4 * l4 + r;
            const size_t o = ((size_t)(b * NTOK + q)) * DMODEL + h * DHEAD + l15;
            #pragma unroll
            for (int f = 0; f < 4; f++) {
                const float v = oacc[qb][f][r] * invq[r];
                const ushort hb = f2bf(v);
                atth[o + 16 * f] = hb;
                attl[o + 16 * f] = f2bf(v - bf2f(hb));
            }
        }
    }
    #undef STAGE_K
    #undef LOAD_V
    #undef STORE_V
}

// ---------------------------------------------------------------- launch
extern "C" void kernel_launch(void* const* d_in, const int* in_sizes, int n_in,
                              void* d_out, int out_size, void* d_ws, size_t ws_size,
                              hipStream_t stream)
{
    const float* x         = (const float*)d_in[0];
    const float* ctx_ppr   = (const float*)d_in[2];
    const float* ctx_delta = (const float*)d_in[3];
    const float* ctx_trust = (const float*)d_in[4];
    const float* W_in      = (const float*)d_in[5];
    const float* b_in      = (const float*)d_in[6];
    const float* W_out     = (const float*)d_in[7];
    const float* b_out     = (const float*)d_in[8];
    const float* alpha     = (const float*)d_in[9];
    const float* tscale    = (const float*)d_in[10];
    const float* Wd1       = (const float*)d_in[11];
    const float* bd1       = (const float*)d_in[12];
    const float* Wd2       = (const float*)d_in[13];
    const float* bd2       = (const float*)d_in[14];
    float* out = (float*)d_out;

    float* ws = (float*)d_ws;
    float* gate_full = ws;                          // 2048 f
    float* col_bias  = ws + 2048;                   // 2048 f
    ushort* u = (ushort*)(ws + 4096);
    ushort* xf   = u;  u += 4194304;
    ushort* wif  = u;  u += 3145728;
    ushort* woh  = u;  u += 1048576;
    ushort* wol  = u;  u += 1048576;
    ushort* qf   = u;  u += 4194304;
    ushort* kf   = u;  u += 4194304;
    ushort* vtf  = u;  u += 4194304;
    ushort* atth = u;  u += 4194304;
    ushort* attl = u;  u += 4194304;                // total ~58 MB

    bias_kernel<<<NTOK, 256, 0, stream>>>(ctx_ppr, ctx_delta, ctx_trust, alpha, tscale,
                                          Wd1, bd1, Wd2, bd2, gate_full, col_bias);
    cvt_f16<<<1024, 256, 0, stream>>>(x,    xf,  1048576);
    cvt_f16<<<768,  256, 0, stream>>>(W_in, wif, 786432);
    cvt_split<<<256, 256, 0, stream>>>(W_out, woh, wol, 262144);

    gemm_f16<<<dim3(24, 32), 256, 0, stream>>>(xf, wif, b_in, qf, kf, vtf, gate_full,
                                               BTOT, 3 * DMODEL, DMODEL);
    attn_f16<<<dim3(16, 32), 256, 0, stream>>>(qf, kf, vtf, col_bias, atth, attl);
    gemm_mfma<2, 0><<<dim3(8, 64), 256, 0, stream>>>(atth, attl, woh, wol, b_out, out,
                                                     nullptr, BTOT, DMODEL, DMODEL);
}

// Round 9
// 296.727 us; speedup vs baseline: 4.5864x; 1.1887x over previous
//
#include <hip/hip_runtime.h>
#include <hip/hip_bf16.h>
#include <hip/hip_fp16.h>
#include <math.h>

// B=2, N=2048, D=1024, H=16, d=64, n_ctx=1024, P=256.
// bias -> cvt (x,W_in -> fp16; W_out -> bf16 hi/lo) -> fp16 QKV MFMA gemm
// -> fp16 swapped-QK MFMA flash attention (QBLK=64, 1024 blocks for TLP)
// -> split-bf16 out-proj MFMA gemm.
// (Resubmission of round-7 kernel: bench infra timed out, measurement still pending.)

#define NTOK 2048
#define DMODEL 1024
#define NHEAD 16
#define DHEAD 64
#define NCTX 1024
#define BTOT 4096

typedef __attribute__((ext_vector_type(8))) short    s8v;   // 8 bf16 bits (4 VGPR)
typedef __attribute__((ext_vector_type(8))) _Float16 h8v;   // 8 fp16 (4 VGPR)
typedef __attribute__((ext_vector_type(4))) float    f4v;
typedef __attribute__((ext_vector_type(4))) ushort   us4;
typedef __attribute__((ext_vector_type(8))) ushort   us8;

__device__ __forceinline__ ushort f2bf(float x) {
    unsigned b = __float_as_uint(x);
    return (ushort)((b + 0x7FFFu + ((b >> 16) & 1u)) >> 16);
}
__device__ __forceinline__ float bf2f(ushort u) {
    return __uint_as_float(((unsigned)u) << 16);
}
__device__ __forceinline__ ushort f2h(float x) {
    return __half_as_ushort(__float2half_rn(x));
}

// global_load_lds width 16: linear LDS dest (wave-uniform base + lane*16), per-lane global src
#define GLDS16(gsrc, ldst) __builtin_amdgcn_global_load_lds(                              \
    (__attribute__((address_space(1))) unsigned int*)(gsrc),                              \
    (__attribute__((address_space(3))) unsigned int*)(ldst), 16, 0, 0)

// ---------------------------------------------------------------- bias kernel (unchanged)
__global__ __launch_bounds__(256)
void bias_kernel(const float* __restrict__ ctx_ppr, const float* __restrict__ ctx_delta,
                 const float* __restrict__ ctx_trust,
                 const float* __restrict__ alpha, const float* __restrict__ tscale,
                 const float* __restrict__ Wd1, const float* __restrict__ bd1,
                 const float* __restrict__ Wd2, const float* __restrict__ bd2,
                 float* __restrict__ gate_full, float* __restrict__ col_bias)
{
    const int i = blockIdx.x;
    const int t = threadIdx.x;
    if (i >= NCTX) {
        if (t == 0) { gate_full[i] = 1.0f; col_bias[i] = 0.0f; }
        return;
    }
    __shared__ float drow[256];
    __shared__ float red[256];
    drow[t] = ctx_delta[i * 256 + t];
    __syncthreads();

    float partial = 0.0f;
    #pragma unroll
    for (int jj = 0; jj < 2; jj++) {
        const int j = t + jj * 256;
        float s = bd1[j];
        const float4* wrow = (const float4*)&Wd1[j * 256];
        const float4* dr   = (const float4*)drow;
        #pragma unroll 8
        for (int p = 0; p < 64; p++) {
            float4 w = wrow[p], dd = dr[p];
            s += w.x * dd.x + w.y * dd.y + w.z * dd.z + w.w * dd.w;
        }
        float g = 0.5f * s * (1.0f + erff(s * 0.70710678118654752f));
        partial += g * Wd2[j];
    }
    red[t] = partial;
    __syncthreads();
    for (int off = 128; off > 0; off >>= 1) {
        if (t < off) red[t] += red[t + off];
        __syncthreads();
    }
    if (t == 0) {
        float ppr = fmaxf(ctx_ppr[i], 1e-8f);
        col_bias[i]  = alpha[0] * logf(ppr) + (red[0] + bd2[0]);
        gate_full[i] = 1.0f / (1.0f + __expf(-(tscale[0] * ctx_trust[i])));
    }
}

// ---------------------------------------------------------------- converts
__global__ __launch_bounds__(256)
void cvt_split(const float* __restrict__ in, ushort* __restrict__ hi,
               ushort* __restrict__ lo, int n4)
{
    for (int i = blockIdx.x * 256 + threadIdx.x; i < n4; i += gridDim.x * 256) {
        float4 v = ((const float4*)in)[i];
        us4 h, l; ushort hb;
        hb = f2bf(v.x); h[0] = hb; l[0] = f2bf(v.x - bf2f(hb));
        hb = f2bf(v.y); h[1] = hb; l[1] = f2bf(v.y - bf2f(hb));
        hb = f2bf(v.z); h[2] = hb; l[2] = f2bf(v.z - bf2f(hb));
        hb = f2bf(v.w); h[3] = hb; l[3] = f2bf(v.w - bf2f(hb));
        ((us4*)hi)[i] = h; ((us4*)lo)[i] = l;
    }
}

__global__ __launch_bounds__(256)
void cvt_f16(const float* __restrict__ in, ushort* __restrict__ out16, int n4)
{
    for (int i = blockIdx.x * 256 + threadIdx.x; i < n4; i += gridDim.x * 256) {
        float4 v = ((const float4*)in)[i];
        us4 h;
        h[0] = f2h(v.x); h[1] = f2h(v.y); h[2] = f2h(v.z); h[3] = f2h(v.w);
        ((us4*)out16)[i] = h;
    }
}

// ---------------------------------------------------------------- fp16 MFMA GEMM (QKV, unchanged)
__global__ __launch_bounds__(256, 3)
void gemm_f16(const ushort* __restrict__ Af, const ushort* __restrict__ Bf,
              const float* __restrict__ bias,
              ushort* __restrict__ qf, ushort* __restrict__ kf,
              ushort* __restrict__ vtf,
              const float* __restrict__ gate_full, int M, int N, int K)
{
    __shared__ ushort AS[4096], BS[4096];

    const int t = threadIdx.x, lane = t & 63, wid = t >> 6;
    const int l15 = lane & 15, l4 = lane >> 4;
    const int wr = wid >> 1, wc = wid & 1;

    const int nwg = gridDim.x * gridDim.y;
    const int lin = blockIdx.y * gridDim.x + blockIdx.x;
    const int w   = (lin & 7) * (nwg >> 3) + (lin >> 3);
    const int bx  = w % gridDim.x, by = w / gridDim.x;
    const int m0 = by * 128, n0 = bx * 128;

    f4v acc[4][4];
    #pragma unroll
    for (int mi = 0; mi < 4; mi++)
        #pragma unroll
        for (int nj = 0; nj < 4; nj++)
            #pragma unroll
            for (int r = 0; r < 4; r++) acc[mi][nj][r] = 0.0f;

    const int srow_l = lane >> 2;
    const int schunk = (lane & 3) ^ ((lane >> 2) & 3) ^ ((lane >> 4) & 3);
    const int rch = l4 ^ (l15 & 3) ^ ((l15 >> 2) & 3);

    const ushort* sp = (wid < 2) ? Af : Bf;
    ushort* dp = (wid < 2) ? AS : BS;
    const int wofs = (wid & 1) * 64;
    const int base0 = (wid < 2) ? m0 : n0;

    for (int k0 = 0; k0 < K; k0 += 32) {
        __syncthreads();
        #pragma unroll
        for (int i = 0; i < 4; i++) {
            const int row = wofs + i * 16 + srow_l;
            GLDS16(sp + (size_t)(base0 + row) * K + k0 + schunk * 8,
                   dp + ((wid & 1) * 4 + i) * 512);
        }
        __syncthreads();

        h8v af[4], bf[4];
        #pragma unroll
        for (int mi = 0; mi < 4; mi++) {
            const int row = wr * 64 + mi * 16 + l15;
            af[mi] = *(const h8v*)&AS[row * 32 + rch * 8];
        }
        #pragma unroll
        for (int nj = 0; nj < 4; nj++) {
            const int row = wc * 64 + nj * 16 + l15;
            bf[nj] = *(const h8v*)&BS[row * 32 + rch * 8];
        }
        #pragma unroll
        for (int mi = 0; mi < 4; mi++)
            #pragma unroll
            for (int nj = 0; nj < 4; nj++)
                acc[mi][nj] = __builtin_amdgcn_mfma_f32_16x16x32_f16(af[mi], bf[nj], acc[mi][nj], 0, 0, 0);
    }

    const int sec = n0 >> 10;
    #pragma unroll
    for (int mi = 0; mi < 4; mi++) {
        const int mbase = m0 + wr * 64 + mi * 16 + l4 * 4;
        const int bb = mbase >> 11, tok0 = mbase & 2047;
        #pragma unroll
        for (int nj = 0; nj < 4; nj++) {
            const int n = n0 + wc * 64 + nj * 16 + l15;
            const float bn = bias[n];
            const int rem = n & 1023, h = rem >> 6, jd = rem & 63;
            if (sec == 2) {
                us4 hv;
                #pragma unroll
                for (int r = 0; r < 4; r++)
                    hv[r] = f2h((acc[mi][nj][r] + bn) * gate_full[tok0 + r]);
                const size_t vb = ((size_t)((bb << 4) + h) * 64 + jd) * NTOK + tok0;
                *(us4*)&vtf[vb] = hv;
            } else {
                ushort* dst = sec ? kf : qf;
                #pragma unroll
                for (int r = 0; r < 4; r++) {
                    const size_t idx = ((size_t)((bb << 4) + h) * NTOK + (tok0 + r)) * 64 + jd;
                    dst[idx] = f2h(acc[mi][nj][r] + bn);
                }
            }
        }
    }
}

// ---------------------------------------------------------------- split-bf16 MFMA GEMM (out-proj, unchanged)
template<int MT, int EPI>
__global__ __launch_bounds__(256)
void gemm_mfma(const ushort* __restrict__ Ah, const ushort* __restrict__ Al,
               const ushort* __restrict__ Bh, const ushort* __restrict__ Bl,
               const float* __restrict__ bias, float* __restrict__ C,
               const float* __restrict__ gate_full, int M, int N, int K)
{
    constexpr int BM = MT * 32;
    __shared__ ushort AhS[BM * 32], AlS[BM * 32], BhS[4096], BlS[4096];

    const int t = threadIdx.x, lane = t & 63, wid = t >> 6;
    const int l15 = lane & 15, l4 = lane >> 4;
    const int wr = wid >> 1, wc = wid & 1;

    const int nwg = gridDim.x * gridDim.y;
    const int lin = blockIdx.y * gridDim.x + blockIdx.x;
    const int w   = (lin & 7) * (nwg >> 3) + (lin >> 3);
    const int bx  = w % gridDim.x, by = w / gridDim.x;
    const int m0 = by * BM, n0 = bx * 128;

    f4v acc[MT][4];
    #pragma unroll
    for (int mi = 0; mi < MT; mi++)
        #pragma unroll
        for (int nj = 0; nj < 4; nj++)
            #pragma unroll
            for (int r = 0; r < 4; r++) acc[mi][nj][r] = 0.0f;

    const int srow_l = lane >> 2;
    const int schunk = (lane & 3) ^ ((lane >> 2) & 3) ^ ((lane >> 4) & 3);
    const int rch = l4 ^ (l15 & 3) ^ ((l15 >> 2) & 3);

    const ushort* sA = (wid == 0) ? Ah : Al;
    const ushort* sB = (wid == 2) ? Bh : Bl;
    ushort* dA = (wid == 0) ? AhS : AlS;
    ushort* dB = (wid == 2) ? BhS : BlS;

    for (int k0 = 0; k0 < K; k0 += 32) {
        __syncthreads();
        if (wid < 2) {
            #pragma unroll
            for (int i = 0; i < BM / 16; i++) {
                const int row = i * 16 + srow_l;
                GLDS16(sA + (size_t)(m0 + row) * K + k0 + schunk * 8, dA + i * 512);
            }
        } else {
            #pragma unroll
            for (int i = 0; i < 8; i++) {
                const int row = i * 16 + srow_l;
                GLDS16(sB + (size_t)(n0 + row) * K + k0 + schunk * 8, dB + i * 512);
            }
        }
        __syncthreads();

        s8v afh[MT], afl[MT], bfh[4], bfl[4];
        #pragma unroll
        for (int mi = 0; mi < MT; mi++) {
            const int row = wr * (MT * 16) + mi * 16 + l15;
            afh[mi] = *(const s8v*)&AhS[row * 32 + rch * 8];
            afl[mi] = *(const s8v*)&AlS[row * 32 + rch * 8];
        }
        #pragma unroll
        for (int nj = 0; nj < 4; nj++) {
            const int row = wc * 64 + nj * 16 + l15;
            bfh[nj] = *(const s8v*)&BhS[row * 32 + rch * 8];
            bfl[nj] = *(const s8v*)&BlS[row * 32 + rch * 8];
        }
        #pragma unroll
        for (int mi = 0; mi < MT; mi++)
            #pragma unroll
            for (int nj = 0; nj < 4; nj++) {
                acc[mi][nj] = __builtin_amdgcn_mfma_f32_16x16x32_bf16(afh[mi], bfh[nj], acc[mi][nj], 0, 0, 0);
                acc[mi][nj] = __builtin_amdgcn_mfma_f32_16x16x32_bf16(afh[mi], bfl[nj], acc[mi][nj], 0, 0, 0);
                acc[mi][nj] = __builtin_amdgcn_mfma_f32_16x16x32_bf16(afl[mi], bfh[nj], acc[mi][nj], 0, 0, 0);
            }
    }

    #pragma unroll
    for (int mi = 0; mi < MT; mi++) {
        #pragma unroll
        for (int nj = 0; nj < 4; nj++) {
            const int n = n0 + wc * 64 + nj * 16 + l15;
            const float bn = bias[n];
            #pragma unroll
            for (int r = 0; r < 4; r++) {
                const int m = m0 + wr * (MT * 16) + mi * 16 + l4 * 4 + r;
                C[(size_t)m * N + n] = acc[mi][nj][r] + bn;
            }
        }
    }
}

// ---------------------------------------------------------------- fp16 swapped-QK flash attention
// QBLK=64: 4 waves, 16 q-rows each -> 1024 blocks (4 resident/CU, 16 waves/CU).
// Same per-q-row arithmetic as round 6/7 (absmax must be bit-identical: 0.0009765625).
__global__ __launch_bounds__(256, 4)
void attn_f16(const ushort* __restrict__ qfp, const ushort* __restrict__ kfp,
              const ushort* __restrict__ vtf, const float* __restrict__ col_bias,
              ushort* __restrict__ atth, ushort* __restrict__ attl)
{
    __shared__ ushort KS[2][4096];   // [buf][key 64][d 64] chunk-swizzled
    __shared__ ushort VS[2][4096];   // [buf][dh 64][kappa 64] pi-perm + swizzled
    __shared__ float  CBS[2][64];

    const int t = threadIdx.x, lane = t & 63, wid = t >> 6;
    const int lin = blockIdx.y * gridDim.x + blockIdx.x;   // 1024 blocks
    const int w   = (lin & 7) * 128 + (lin >> 3);          // bijective XCD swizzle
    const int bh  = w >> 5, qt = w & 31;

    const size_t qkbase = (size_t)bh * (NTOK * DHEAD);
    const size_t vtbase = (size_t)bh * (DHEAD * NTOK);
    const int l15 = lane & 15, l4 = lane >> 4;
    const int q0 = qt * 64 + wid * 16;

    // Q fragments (B-operand): lane -> Q[q0+l15][32s+8l4+0..7]
    h8v qf[2];
    #pragma unroll
    for (int s = 0; s < 2; s++)
        qf[s] = *(const h8v*)&qfp[qkbase + (size_t)(q0 + l15) * 64 + 32 * s + 8 * l4];

    f4v oacc[4];
    #pragma unroll
    for (int f = 0; f < 4; f++)
        #pragma unroll
        for (int r = 0; r < 4; r++) oacc[f][r] = 0.0f;
    float mreg = -INFINITY;
    float sreg = 0.0f;

    // V reg-staging (waves 2,3: 32 dh rows each)
    us8 vreg[4];
    const int vj = lane & 7, vdh0 = lane >> 3;
    const int k0c  = 4 * (vj >> 2) + 2 * (vj & 1);
    const int off0 = ((vj >> 1) & 1) * 8;

    #define STAGE_K(nb, kt) do {                                                          \
        _Pragma("unroll")                                                                 \
        for (int i_ = 0; i_ < 4; i_++) {                                                  \
            const int row_ = wid * 32 + i_ * 8 + (lane >> 3);                             \
            const int sc_  = ((lane & 7) ^ (row_ & 7)) * 8;                               \
            GLDS16(kfp + qkbase + (size_t)((kt) + row_) * 64 + sc_,                       \
                   &KS[nb][0] + (wid * 4 + i_) * 512);                                    \
        }                                                                                 \
        if (wid == 0 && lane < 16) GLDS16(col_bias + (kt) + lane * 4, &CBS[nb][0]);       \
    } while (0)

    #define LOAD_V(kt) do {                                                               \
        _Pragma("unroll")                                                                 \
        for (int i_ = 0; i_ < 4; i_++) {                                                  \
            const int dh_ = (wid - 2) * 32 + 8 * i_ + vdh0;                               \
            vreg[i_] = *(const us8*)&vtf[vtbase + (size_t)dh_ * NTOK + (kt) + 8 * vj];    \
        }                                                                                 \
    } while (0)

    #define STORE_V(nb) do {                                                              \
        char* dp_ = (char*)&VS[nb][0];                                                    \
        _Pragma("unroll")                                                                 \
        for (int i_ = 0; i_ < 4; i_++) {                                                  \
            const int dh_ = (wid - 2) * 32 + 8 * i_ + vdh0;                               \
            const int b0_ = dh_ * 128 + ((k0c ^ (dh_ & 7)) * 16) + off0;                  \
            const int b1_ = dh_ * 128 + (((k0c + 1) ^ (dh_ & 7)) * 16) + off0;            \
            us4 lo4_, hi4_;                                                               \
            lo4_[0] = vreg[i_][0]; lo4_[1] = vreg[i_][1];                                 \
            lo4_[2] = vreg[i_][2]; lo4_[3] = vreg[i_][3];                                 \
            hi4_[0] = vreg[i_][4]; hi4_[1] = vreg[i_][5];                                 \
            hi4_[2] = vreg[i_][6]; hi4_[3] = vreg[i_][7];                                 \
            *(us4*)(dp_ + b0_) = lo4_;                                                    \
            *(us4*)(dp_ + b1_) = hi4_;                                                    \
        }                                                                                 \
    } while (0)

    if (wid < 2) STAGE_K(0, 0); else { LOAD_V(0); STORE_V(0); }
    __syncthreads();

    int cur = 0;
    for (int kt = 0; kt < 32; kt++) {
        const int nxt = cur ^ 1;
        if (kt < 31) { if (wid < 2) STAGE_K(nxt, (kt + 1) * 64); else LOAD_V((kt + 1) * 64); }

        // ---- QK^T: sa[g], row=key=16g+4l4+r, col=q=l15
        f4v sa[4];
        #pragma unroll
        for (int g = 0; g < 4; g++)
            #pragma unroll
            for (int r = 0; r < 4; r++) sa[g][r] = 0.0f;
        __builtin_amdgcn_s_setprio(1);
        #pragma unroll
        for (int s = 0; s < 2; s++) {
            #pragma unroll
            for (int g = 0; g < 4; g++) {
                const int row = 16 * g + l15;
                const int idx = row * 64 + (((4 * s + l4) ^ (l15 & 7))) * 8;
                h8v kfr = *(const h8v*)&KS[cur][idx];
                sa[g] = __builtin_amdgcn_mfma_f32_16x16x32_f16(kfr, qf[s], sa[g], 0, 0, 0);
            }
        }
        __builtin_amdgcn_s_setprio(0);

        // ---- logits + defer-max online softmax (key dim in-lane)
        float sv[4][4], smax = -INFINITY;
        #pragma unroll
        for (int g = 0; g < 4; g++)
            #pragma unroll
            for (int r = 0; r < 4; r++) {
                const float x = sa[g][r] * 0.125f + CBS[cur][16 * g + 4 * l4 + r];
                sv[g][r] = x;
                smax = fmaxf(smax, x);
            }
        if (__any(smax > mreg + 8.0f)) {
            float mx = smax;
            mx = fmaxf(mx, __shfl_xor(mx, 16));
            mx = fmaxf(mx, __shfl_xor(mx, 32));
            const float mnew = fmaxf(mreg, mx);
            const float fs = __expf(mreg - mnew);   // first tile: exp(-inf)=0
            mreg = mnew;
            sreg *= fs;
            float fq[4];
            #pragma unroll
            for (int r = 0; r < 4; r++) fq[r] = __shfl(fs, 4 * l4 + r);
            #pragma unroll
            for (int f = 0; f < 4; f++)
                #pragma unroll
                for (int r = 0; r < 4; r++) oacc[f][r] *= fq[r];
        }

        // ---- p = exp(s - m), pack to fp16 PV A-frags via pi (pure registers)
        union H8 { h8v v; __half2 h2[4]; };
        H8 pa[2];
        {
            float pv[4][4];
            float acc_s = 0.0f;
            #pragma unroll
            for (int g = 0; g < 4; g++)
                #pragma unroll
                for (int r = 0; r < 4; r++) {
                    const float p = __expf(sv[g][r] - mreg);  // p <= e^8, fits fp16
                    pv[g][r] = p;
                    acc_s += p;
                }
            sreg += acc_s;
            #pragma unroll
            for (int s = 0; s < 2; s++)
                #pragma unroll
                for (int a = 0; a < 2; a++) {
                    const int g = 2 * s + a;
                    pa[s].h2[2 * a]     = __float22half2_rn(make_float2(pv[g][0], pv[g][1]));
                    pa[s].h2[2 * a + 1] = __float22half2_rn(make_float2(pv[g][2], pv[g][3]));
                }
        }

        // ---- PV: O[q][dh] += P pi-slots x V pi-layout
        __builtin_amdgcn_s_setprio(1);
        #pragma unroll
        for (int s = 0; s < 2; s++) {
            #pragma unroll
            for (int f = 0; f < 4; f++) {
                const int row = 16 * f + l15;
                const int idx = row * 64 + (((4 * s + l4) ^ (l15 & 7))) * 8;
                h8v vfr = *(const h8v*)&VS[cur][idx];
                oacc[f] = __builtin_amdgcn_mfma_f32_16x16x32_f16(pa[s].v, vfr, oacc[f], 0, 0, 0);
            }
        }
        __builtin_amdgcn_s_setprio(0);

        if (kt < 31 && wid >= 2) STORE_V(nxt);
        __syncthreads();
        cur = nxt;
    }

    // ---- epilogue: reduce l across l4 groups, normalize, emit att hi/lo bf16
    const int b = bh >> 4, h = bh & 15;
    {
        float ts = sreg;
        ts += __shfl_xor(ts, 16);
        ts += __shfl_xor(ts, 32);
        const float inv = 1.0f / ts;
        float invq[4];
        #pragma unroll
        for (int r = 0; r < 4; r++) invq[r] = __shfl(inv, 4 * l4 + r);
        #pragma unroll
        for (int r = 0; r < 4; r++) {
            const int q = q0 + 4 * l4 + r;
            const size_t o = ((size_t)(b * NTOK + q)) * DMODEL + h * DHEAD + l15;
            #pragma unroll
            for (int f = 0; f < 4; f++) {
                const float v = oacc[f][r] * invq[r];
                const ushort hb = f2bf(v);
                atth[o + 16 * f] = hb;
                attl[o + 16 * f] = f2bf(v - bf2f(hb));
            }
        }
    }
    #undef STAGE_K
    #undef LOAD_V
    #undef STORE_V
}

// ---------------------------------------------------------------- launch
extern "C" void kernel_launch(void* const* d_in, const int* in_sizes, int n_in,
                              void* d_out, int out_size, void* d_ws, size_t ws_size,
                              hipStream_t stream)
{
    const float* x         = (const float*)d_in[0];
    const float* ctx_ppr   = (const float*)d_in[2];
    const float* ctx_delta = (const float*)d_in[3];
    const float* ctx_trust = (const float*)d_in[4];
    const float* W_in      = (const float*)d_in[5];
    const float* b_in      = (const float*)d_in[6];
    const float* W_out     = (const float*)d_in[7];
    const float* b_out     = (const float*)d_in[8];
    const float* alpha     = (const float*)d_in[9];
    const float* tscale    = (const float*)d_in[10];
    const float* Wd1       = (const float*)d_in[11];
    const float* bd1       = (const float*)d_in[12];
    const float* Wd2       = (const float*)d_in[13];
    const float* bd2       = (const float*)d_in[14];
    float* out = (float*)d_out;

    float* ws = (float*)d_ws;
    float* gate_full = ws;                          // 2048 f
    float* col_bias  = ws + 2048;                   // 2048 f
    ushort* u = (ushort*)(ws + 4096);
    ushort* xf   = u;  u += 4194304;
    ushort* wif  = u;  u += 3145728;
    ushort* woh  = u;  u += 1048576;
    ushort* wol  = u;  u += 1048576;
    ushort* qf   = u;  u += 4194304;
    ushort* kf   = u;  u += 4194304;
    ushort* vtf  = u;  u += 4194304;
    ushort* atth = u;  u += 4194304;
    ushort* attl = u;  u += 4194304;                // total ~58 MB

    bias_kernel<<<NTOK, 256, 0, stream>>>(ctx_ppr, ctx_delta, ctx_trust, alpha, tscale,
                                          Wd1, bd1, Wd2, bd2, gate_full, col_bias);
    cvt_f16<<<1024, 256, 0, stream>>>(x,    xf,  1048576);
    cvt_f16<<<768,  256, 0, stream>>>(W_in, wif, 786432);
    cvt_split<<<256, 256, 0, stream>>>(W_out, woh, wol, 262144);

    gemm_f16<<<dim3(24, 32), 256, 0, stream>>>(xf, wif, b_in, qf, kf, vtf, gate_full,
                                               BTOT, 3 * DMODEL, DMODEL);
    attn_f16<<<dim3(32, 32), 256, 0, stream>>>(qf, kf, vtf, col_bias, atth, attl);
    gemm_mfma<2, 0><<<dim3(8, 64), 256, 0, stream>>>(atth, attl, woh, wol, b_out, out,
                                                     nullptr, BTOT, DMODEL, DMODEL);
}

// Round 11
// 275.220 us; speedup vs baseline: 4.9448x; 1.0781x over previous
//
#include <hip/hip_runtime.h>
#include <hip/hip_bf16.h>
#include <hip/hip_fp16.h>
#include <math.h>

// B=2, N=2048, D=1024, H=16, d=64, n_ctx=1024, P=256.
// bias -> fused cvt (x, W_in, W_out -> fp16) -> fp16 QKV MFMA gemm
// -> fp16 swapped-QK MFMA flash attention (QBLK=64, 1024 blocks) -> fp16 out-proj gemm.
// (Resubmission of round-9 kernel: bench infra timed out, measurement still pending.)

#define NTOK 2048
#define DMODEL 1024
#define NHEAD 16
#define DHEAD 64
#define NCTX 1024
#define BTOT 4096

typedef __attribute__((ext_vector_type(8))) _Float16 h8v;   // 8 fp16 (4 VGPR)
typedef __attribute__((ext_vector_type(4))) float    f4v;
typedef __attribute__((ext_vector_type(4))) ushort   us4;
typedef __attribute__((ext_vector_type(8))) ushort   us8;

__device__ __forceinline__ ushort f2h(float x) {
    return __half_as_ushort(__float2half_rn(x));
}

// global_load_lds width 16: linear LDS dest (wave-uniform base + lane*16), per-lane global src
#define GLDS16(gsrc, ldst) __builtin_amdgcn_global_load_lds(                              \
    (__attribute__((address_space(1))) unsigned int*)(gsrc),                              \
    (__attribute__((address_space(3))) unsigned int*)(ldst), 16, 0, 0)

// ---------------------------------------------------------------- bias kernel (unchanged)
__global__ __launch_bounds__(256)
void bias_kernel(const float* __restrict__ ctx_ppr, const float* __restrict__ ctx_delta,
                 const float* __restrict__ ctx_trust,
                 const float* __restrict__ alpha, const float* __restrict__ tscale,
                 const float* __restrict__ Wd1, const float* __restrict__ bd1,
                 const float* __restrict__ Wd2, const float* __restrict__ bd2,
                 float* __restrict__ gate_full, float* __restrict__ col_bias)
{
    const int i = blockIdx.x;
    const int t = threadIdx.x;
    if (i >= NCTX) {
        if (t == 0) { gate_full[i] = 1.0f; col_bias[i] = 0.0f; }
        return;
    }
    __shared__ float drow[256];
    __shared__ float red[256];
    drow[t] = ctx_delta[i * 256 + t];
    __syncthreads();

    float partial = 0.0f;
    #pragma unroll
    for (int jj = 0; jj < 2; jj++) {
        const int j = t + jj * 256;
        float s = bd1[j];
        const float4* wrow = (const float4*)&Wd1[j * 256];
        const float4* dr   = (const float4*)drow;
        #pragma unroll 8
        for (int p = 0; p < 64; p++) {
            float4 w = wrow[p], dd = dr[p];
            s += w.x * dd.x + w.y * dd.y + w.z * dd.z + w.w * dd.w;
        }
        float g = 0.5f * s * (1.0f + erff(s * 0.70710678118654752f));
        partial += g * Wd2[j];
    }
    red[t] = partial;
    __syncthreads();
    for (int off = 128; off > 0; off >>= 1) {
        if (t < off) red[t] += red[t + off];
        __syncthreads();
    }
    if (t == 0) {
        float ppr = fmaxf(ctx_ppr[i], 1e-8f);
        col_bias[i]  = alpha[0] * logf(ppr) + (red[0] + bd2[0]);
        gate_full[i] = 1.0f / (1.0f + __expf(-(tscale[0] * ctx_trust[i])));
    }
}

// ---------------------------------------------------------------- fused fp32 -> fp16 convert
// x: 1048576 float4 | W_in: 786432 | W_out: 262144  (total 2097152 float4)
__global__ __launch_bounds__(256)
void cvt_all(const float* __restrict__ x, const float* __restrict__ wi,
             const float* __restrict__ wo,
             ushort* __restrict__ xf, ushort* __restrict__ wif, ushort* __restrict__ wof)
{
    for (int i = blockIdx.x * 256 + threadIdx.x; i < 2097152; i += gridDim.x * 256) {
        const float* src; ushort* dst; int j;
        if (i < 1048576)      { src = x;  dst = xf;  j = i; }
        else if (i < 1835008) { src = wi; dst = wif; j = i - 1048576; }
        else                  { src = wo; dst = wof; j = i - 1835008; }
        float4 v = ((const float4*)src)[j];
        us4 h;
        h[0] = f2h(v.x); h[1] = f2h(v.y); h[2] = f2h(v.z); h[3] = f2h(v.w);
        ((us4*)dst)[j] = h;
    }
}

// ---------------------------------------------------------------- fp16 MFMA GEMM
// C = A @ B^T + bias. A [M][K] fp16, B [N][K] fp16, fp32 accum. BM=MT*32, BN=128, BK=32.
// EPI=1: scatter q/k fp16 [bh][tok][64] + V^T fp16 [bh][64][tok] gated (QKV).
// EPI=0: C[m*N+n] = acc + bias[n], fp32 out (out-proj).
template<int MT, int EPI>
__global__ __launch_bounds__(256, 3)
void gemm_f16(const ushort* __restrict__ Af, const ushort* __restrict__ Bf,
              const float* __restrict__ bias, float* __restrict__ C,
              ushort* __restrict__ qf, ushort* __restrict__ kf,
              ushort* __restrict__ vtf,
              const float* __restrict__ gate_full, int M, int N, int K)
{
    constexpr int BM = MT * 32;
    __shared__ ushort AS[BM * 32], BS[4096];

    const int t = threadIdx.x, lane = t & 63, wid = t >> 6;
    const int l15 = lane & 15, l4 = lane >> 4;
    const int wr = wid >> 1, wc = wid & 1;

    const int nwg = gridDim.x * gridDim.y;
    const int lin = blockIdx.y * gridDim.x + blockIdx.x;
    const int w   = (lin & 7) * (nwg >> 3) + (lin >> 3);
    const int bx  = w % gridDim.x, by = w / gridDim.x;
    const int m0 = by * BM, n0 = bx * 128;

    f4v acc[MT][4];
    #pragma unroll
    for (int mi = 0; mi < MT; mi++)
        #pragma unroll
        for (int nj = 0; nj < 4; nj++)
            #pragma unroll
            for (int r = 0; r < 4; r++) acc[mi][nj][r] = 0.0f;

    const int srow_l = lane >> 2;
    const int schunk = (lane & 3) ^ ((lane >> 2) & 3) ^ ((lane >> 4) & 3);
    const int rch = l4 ^ (l15 & 3) ^ ((l15 >> 2) & 3);

    for (int k0 = 0; k0 < K; k0 += 32) {
        __syncthreads();
        if (wid < 2) {
            #pragma unroll
            for (int i = 0; i < MT; i++) {      // wave stages MT*16 A-rows
                const int row = (wid & 1) * (MT * 16) + i * 16 + srow_l;
                GLDS16(Af + (size_t)(m0 + row) * K + k0 + schunk * 8,
                       AS + ((wid & 1) * MT + i) * 512);
            }
        } else {
            #pragma unroll
            for (int i = 0; i < 4; i++) {       // wave stages 64 B-rows
                const int row = (wid & 1) * 64 + i * 16 + srow_l;
                GLDS16(Bf + (size_t)(n0 + row) * K + k0 + schunk * 8,
                       BS + ((wid & 1) * 4 + i) * 512);
            }
        }
        __syncthreads();

        h8v af[MT], bf[4];
        #pragma unroll
        for (int mi = 0; mi < MT; mi++) {
            const int row = wr * (MT * 16) + mi * 16 + l15;
            af[mi] = *(const h8v*)&AS[row * 32 + rch * 8];
        }
        #pragma unroll
        for (int nj = 0; nj < 4; nj++) {
            const int row = wc * 64 + nj * 16 + l15;
            bf[nj] = *(const h8v*)&BS[row * 32 + rch * 8];
        }
        #pragma unroll
        for (int mi = 0; mi < MT; mi++)
            #pragma unroll
            for (int nj = 0; nj < 4; nj++)
                acc[mi][nj] = __builtin_amdgcn_mfma_f32_16x16x32_f16(af[mi], bf[nj], acc[mi][nj], 0, 0, 0);
    }

    if (EPI == 0) {
        #pragma unroll
        for (int mi = 0; mi < MT; mi++) {
            #pragma unroll
            for (int nj = 0; nj < 4; nj++) {
                const int n = n0 + wc * 64 + nj * 16 + l15;
                const float bn = bias[n];
                #pragma unroll
                for (int r = 0; r < 4; r++) {
                    const int m = m0 + wr * (MT * 16) + mi * 16 + l4 * 4 + r;
                    C[(size_t)m * N + n] = acc[mi][nj][r] + bn;
                }
            }
        }
    } else {
        const int sec = n0 >> 10;               // 0=q 1=k 2=v (uniform per block)
        #pragma unroll
        for (int mi = 0; mi < MT; mi++) {
            const int mbase = m0 + wr * (MT * 16) + mi * 16 + l4 * 4;
            const int bb = mbase >> 11, tok0 = mbase & 2047;
            #pragma unroll
            for (int nj = 0; nj < 4; nj++) {
                const int n = n0 + wc * 64 + nj * 16 + l15;
                const float bn = bias[n];
                const int rem = n & 1023, h = rem >> 6, jd = rem & 63;
                if (sec == 2) {
                    us4 hv;
                    #pragma unroll
                    for (int r = 0; r < 4; r++)
                        hv[r] = f2h((acc[mi][nj][r] + bn) * gate_full[tok0 + r]);
                    const size_t vb = ((size_t)((bb << 4) + h) * 64 + jd) * NTOK + tok0;
                    *(us4*)&vtf[vb] = hv;
                } else {
                    ushort* dst = sec ? kf : qf;
                    #pragma unroll
                    for (int r = 0; r < 4; r++) {
                        const size_t idx = ((size_t)((bb << 4) + h) * NTOK + (tok0 + r)) * 64 + jd;
                        dst[idx] = f2h(acc[mi][nj][r] + bn);
                    }
                }
            }
        }
    }
}

// ---------------------------------------------------------------- fp16 swapped-QK flash attention
// QBLK=64: 4 waves, 16 q-rows each -> 1024 blocks (4 resident/CU). Arithmetic identical to
// round 9 except epilogue emits att as plain fp16 (consumed by fp16 out-proj).
__global__ __launch_bounds__(256, 4)
void attn_f16(const ushort* __restrict__ qfp, const ushort* __restrict__ kfp,
              const ushort* __restrict__ vtf, const float* __restrict__ col_bias,
              ushort* __restrict__ attf)
{
    __shared__ ushort KS[2][4096];   // [buf][key 64][d 64] chunk-swizzled
    __shared__ ushort VS[2][4096];   // [buf][dh 64][kappa 64] pi-perm + swizzled
    __shared__ float  CBS[2][64];

    const int t = threadIdx.x, lane = t & 63, wid = t >> 6;
    const int lin = blockIdx.y * gridDim.x + blockIdx.x;   // 1024 blocks
    const int w   = (lin & 7) * 128 + (lin >> 3);          // bijective XCD swizzle
    const int bh  = w >> 5, qt = w & 31;

    const size_t qkbase = (size_t)bh * (NTOK * DHEAD);
    const size_t vtbase = (size_t)bh * (DHEAD * NTOK);
    const int l15 = lane & 15, l4 = lane >> 4;
    const int q0 = qt * 64 + wid * 16;

    h8v qf[2];
    #pragma unroll
    for (int s = 0; s < 2; s++)
        qf[s] = *(const h8v*)&qfp[qkbase + (size_t)(q0 + l15) * 64 + 32 * s + 8 * l4];

    f4v oacc[4];
    #pragma unroll
    for (int f = 0; f < 4; f++)
        #pragma unroll
        for (int r = 0; r < 4; r++) oacc[f][r] = 0.0f;
    float mreg = -INFINITY;
    float sreg = 0.0f;

    us8 vreg[4];
    const int vj = lane & 7, vdh0 = lane >> 3;
    const int k0c  = 4 * (vj >> 2) + 2 * (vj & 1);
    const int off0 = ((vj >> 1) & 1) * 8;

    #define STAGE_K(nb, kt) do {                                                          \
        _Pragma("unroll")                                                                 \
        for (int i_ = 0; i_ < 4; i_++) {                                                  \
            const int row_ = wid * 32 + i_ * 8 + (lane >> 3);                             \
            const int sc_  = ((lane & 7) ^ (row_ & 7)) * 8;                               \
            GLDS16(kfp + qkbase + (size_t)((kt) + row_) * 64 + sc_,                       \
                   &KS[nb][0] + (wid * 4 + i_) * 512);                                    \
        }                                                                                 \
        if (wid == 0 && lane < 16) GLDS16(col_bias + (kt) + lane * 4, &CBS[nb][0]);       \
    } while (0)

    #define LOAD_V(kt) do {                                                               \
        _Pragma("unroll")                                                                 \
        for (int i_ = 0; i_ < 4; i_++) {                                                  \
            const int dh_ = (wid - 2) * 32 + 8 * i_ + vdh0;                               \
            vreg[i_] = *(const us8*)&vtf[vtbase + (size_t)dh_ * NTOK + (kt) + 8 * vj];    \
        }                                                                                 \
    } while (0)

    #define STORE_V(nb) do {                                                              \
        char* dp_ = (char*)&VS[nb][0];                                                    \
        _Pragma("unroll")                                                                 \
        for (int i_ = 0; i_ < 4; i_++) {                                                  \
            const int dh_ = (wid - 2) * 32 + 8 * i_ + vdh0;                               \
            const int b0_ = dh_ * 128 + ((k0c ^ (dh_ & 7)) * 16) + off0;                  \
            const int b1_ = dh_ * 128 + (((k0c + 1) ^ (dh_ & 7)) * 16) + off0;            \
            us4 lo4_, hi4_;                                                               \
            lo4_[0] = vreg[i_][0]; lo4_[1] = vreg[i_][1];                                 \
            lo4_[2] = vreg[i_][2]; lo4_[3] = vreg[i_][3];                                 \
            hi4_[0] = vreg[i_][4]; hi4_[1] = vreg[i_][5];                                 \
            hi4_[2] = vreg[i_][6]; hi4_[3] = vreg[i_][7];                                 \
            *(us4*)(dp_ + b0_) = lo4_;                                                    \
            *(us4*)(dp_ + b1_) = hi4_;                                                    \
        }                                                                                 \
    } while (0)

    if (wid < 2) STAGE_K(0, 0); else { LOAD_V(0); STORE_V(0); }
    __syncthreads();

    int cur = 0;
    for (int kt = 0; kt < 32; kt++) {
        const int nxt = cur ^ 1;
        if (kt < 31) { if (wid < 2) STAGE_K(nxt, (kt + 1) * 64); else LOAD_V((kt + 1) * 64); }

        // ---- QK^T: sa[g], row=key=16g+4l4+r, col=q=l15
        f4v sa[4];
        #pragma unroll
        for (int g = 0; g < 4; g++)
            #pragma unroll
            for (int r = 0; r < 4; r++) sa[g][r] = 0.0f;
        __builtin_amdgcn_s_setprio(1);
        #pragma unroll
        for (int s = 0; s < 2; s++) {
            #pragma unroll
            for (int g = 0; g < 4; g++) {
                const int row = 16 * g + l15;
                const int idx = row * 64 + (((4 * s + l4) ^ (l15 & 7))) * 8;
                h8v kfr = *(const h8v*)&KS[cur][idx];
                sa[g] = __builtin_amdgcn_mfma_f32_16x16x32_f16(kfr, qf[s], sa[g], 0, 0, 0);
            }
        }
        __builtin_amdgcn_s_setprio(0);

        // ---- logits + defer-max online softmax (key dim in-lane)
        float sv[4][4], smax = -INFINITY;
        #pragma unroll
        for (int g = 0; g < 4; g++)
            #pragma unroll
            for (int r = 0; r < 4; r++) {
                const float x = sa[g][r] * 0.125f + CBS[cur][16 * g + 4 * l4 + r];
                sv[g][r] = x;
                smax = fmaxf(smax, x);
            }
        if (__any(smax > mreg + 8.0f)) {
            float mx = smax;
            mx = fmaxf(mx, __shfl_xor(mx, 16));
            mx = fmaxf(mx, __shfl_xor(mx, 32));
            const float mnew = fmaxf(mreg, mx);
            const float fs = __expf(mreg - mnew);   // first tile: exp(-inf)=0
            mreg = mnew;
            sreg *= fs;
            float fq[4];
            #pragma unroll
            for (int r = 0; r < 4; r++) fq[r] = __shfl(fs, 4 * l4 + r);
            #pragma unroll
            for (int f = 0; f < 4; f++)
                #pragma unroll
                for (int r = 0; r < 4; r++) oacc[f][r] *= fq[r];
        }

        // ---- p = exp(s - m), pack to fp16 PV A-frags via pi (pure registers)
        union H8 { h8v v; __half2 h2[4]; };
        H8 pa[2];
        {
            float pv[4][4];
            float acc_s = 0.0f;
            #pragma unroll
            for (int g = 0; g < 4; g++)
                #pragma unroll
                for (int r = 0; r < 4; r++) {
                    const float p = __expf(sv[g][r] - mreg);  // p <= e^8, fits fp16
                    pv[g][r] = p;
                    acc_s += p;
                }
            sreg += acc_s;
            #pragma unroll
            for (int s = 0; s < 2; s++)
                #pragma unroll
                for (int a = 0; a < 2; a++) {
                    const int g = 2 * s + a;
                    pa[s].h2[2 * a]     = __float22half2_rn(make_float2(pv[g][0], pv[g][1]));
                    pa[s].h2[2 * a + 1] = __float22half2_rn(make_float2(pv[g][2], pv[g][3]));
                }
        }

        // ---- PV: O[q][dh] += P pi-slots x V pi-layout
        __builtin_amdgcn_s_setprio(1);
        #pragma unroll
        for (int s = 0; s < 2; s++) {
            #pragma unroll
            for (int f = 0; f < 4; f++) {
                const int row = 16 * f + l15;
                const int idx = row * 64 + (((4 * s + l4) ^ (l15 & 7))) * 8;
                h8v vfr = *(const h8v*)&VS[cur][idx];
                oacc[f] = __builtin_amdgcn_mfma_f32_16x16x32_f16(pa[s].v, vfr, oacc[f], 0, 0, 0);
            }
        }
        __builtin_amdgcn_s_setprio(0);

        if (kt < 31 && wid >= 2) STORE_V(nxt);
        __syncthreads();
        cur = nxt;
    }

    // ---- epilogue: reduce l across l4 groups, normalize, emit att fp16 [B][N][D]
    const int b = bh >> 4, h = bh & 15;
    {
        float ts = sreg;
        ts += __shfl_xor(ts, 16);
        ts += __shfl_xor(ts, 32);
        const float inv = 1.0f / ts;
        float invq[4];
        #pragma unroll
        for (int r = 0; r < 4; r++) invq[r] = __shfl(inv, 4 * l4 + r);
        #pragma unroll
        for (int r = 0; r < 4; r++) {
            const int q = q0 + 4 * l4 + r;
            const size_t o = ((size_t)(b * NTOK + q)) * DMODEL + h * DHEAD + l15;
            #pragma unroll
            for (int f = 0; f < 4; f++)
                attf[o + 16 * f] = f2h(oacc[f][r] * invq[r]);
        }
    }
    #undef STAGE_K
    #undef LOAD_V
    #undef STORE_V
}

// ---------------------------------------------------------------- launch
extern "C" void kernel_launch(void* const* d_in, const int* in_sizes, int n_in,
                              void* d_out, int out_size, void* d_ws, size_t ws_size,
                              hipStream_t stream)
{
    const float* x         = (const float*)d_in[0];
    const float* ctx_ppr   = (const float*)d_in[2];
    const float* ctx_delta = (const float*)d_in[3];
    const float* ctx_trust = (const float*)d_in[4];
    const float* W_in      = (const float*)d_in[5];
    const float* b_in      = (const float*)d_in[6];
    const float* W_out     = (const float*)d_in[7];
    const float* b_out     = (const float*)d_in[8];
    const float* alpha     = (const float*)d_in[9];
    const float* tscale    = (const float*)d_in[10];
    const float* Wd1       = (const float*)d_in[11];
    const float* bd1       = (const float*)d_in[12];
    const float* Wd2       = (const float*)d_in[13];
    const float* bd2       = (const float*)d_in[14];
    float* out = (float*)d_out;

    float* ws = (float*)d_ws;
    float* gate_full = ws;                          // 2048 f
    float* col_bias  = ws + 2048;                   // 2048 f
    ushort* u = (ushort*)(ws + 4096);
    ushort* xf   = u;  u += 4194304;
    ushort* wif  = u;  u += 3145728;
    ushort* wof  = u;  u += 1048576;
    ushort* qf   = u;  u += 4194304;
    ushort* kf   = u;  u += 4194304;
    ushort* vtf  = u;  u += 4194304;
    ushort* attf = u;  u += 4194304;                // total ~48 MB

    bias_kernel<<<NTOK, 256, 0, stream>>>(ctx_ppr, ctx_delta, ctx_trust, alpha, tscale,
                                          Wd1, bd1, Wd2, bd2, gate_full, col_bias);
    cvt_all<<<2048, 256, 0, stream>>>(x, W_in, W_out, xf, wif, wof);

    gemm_f16<4, 1><<<dim3(24, 32), 256, 0, stream>>>(xf, wif, b_in, nullptr,
                                                     qf, kf, vtf, gate_full,
                                                     BTOT, 3 * DMODEL, DMODEL);
    attn_f16<<<dim3(32, 32), 256, 0, stream>>>(qf, kf, vtf, col_bias, attf);
    gemm_f16<2, 0><<<dim3(8, 64), 256, 0, stream>>>(attf, wof, b_out, out,
                                                    nullptr, nullptr, nullptr, nullptr,
                                                    BTOT, DMODEL, DMODEL);
}

// Round 12
// 271.094 us; speedup vs baseline: 5.0201x; 1.0152x over previous
//
#include <hip/hip_runtime.h>
#include <hip/hip_bf16.h>
#include <hip/hip_fp16.h>
#include <math.h>

// B=2, N=2048, D=1024, H=16, d=64, n_ctx=1024, P=256.
// bias (emits col_bias in exp2 domain) -> fused cvt (+tail init) -> fp16 QKV MFMA gemm
// -> fp16 swapped-QK MFMA flash attention (exp2 softmax, lsum-via-MFMA) -> fp16 out-proj.

#define NTOK 2048
#define DMODEL 1024
#define NHEAD 16
#define DHEAD 64
#define NCTX 1024
#define BTOT 4096
#define LOG2E 1.4426950408889634f

typedef __attribute__((ext_vector_type(8))) _Float16 h8v;   // 8 fp16 (4 VGPR)
typedef __attribute__((ext_vector_type(4))) float    f4v;
typedef __attribute__((ext_vector_type(4))) ushort   us4;
typedef __attribute__((ext_vector_type(8))) ushort   us8;

__device__ __forceinline__ ushort f2h(float x) {
    return __half_as_ushort(__float2half_rn(x));
}

#if __has_builtin(__builtin_amdgcn_exp2f)
#define EXP2F(x) __builtin_amdgcn_exp2f(x)
#else
#define EXP2F(x) exp2f(x)
#endif

// global_load_lds width 16: linear LDS dest (wave-uniform base + lane*16), per-lane global src
#define GLDS16(gsrc, ldst) __builtin_amdgcn_global_load_lds(                              \
    (__attribute__((address_space(1))) unsigned int*)(gsrc),                              \
    (__attribute__((address_space(3))) unsigned int*)(ldst), 16, 0, 0)

// ---------------------------------------------------------------- bias kernel (ctx rows only)
// col_bias emitted PRE-SCALED by log2(e) (attn consumes it in exp2 domain).
__global__ __launch_bounds__(256)
void bias_kernel(const float* __restrict__ ctx_ppr, const float* __restrict__ ctx_delta,
                 const float* __restrict__ ctx_trust,
                 const float* __restrict__ alpha, const float* __restrict__ tscale,
                 const float* __restrict__ Wd1, const float* __restrict__ bd1,
                 const float* __restrict__ Wd2, const float* __restrict__ bd2,
                 float* __restrict__ gate_full, float* __restrict__ col_bias)
{
    const int i = blockIdx.x;   // 0..NCTX-1
    const int t = threadIdx.x;
    __shared__ float drow[256];
    __shared__ float red[256];
    drow[t] = ctx_delta[i * 256 + t];
    __syncthreads();

    float partial = 0.0f;
    #pragma unroll
    for (int jj = 0; jj < 2; jj++) {
        const int j = t + jj * 256;
        float s = bd1[j];
        const float4* wrow = (const float4*)&Wd1[j * 256];
        const float4* dr   = (const float4*)drow;
        #pragma unroll 8
        for (int p = 0; p < 64; p++) {
            float4 w = wrow[p], dd = dr[p];
            s += w.x * dd.x + w.y * dd.y + w.z * dd.z + w.w * dd.w;
        }
        float g = 0.5f * s * (1.0f + erff(s * 0.70710678118654752f));
        partial += g * Wd2[j];
    }
    red[t] = partial;
    __syncthreads();
    for (int off = 128; off > 0; off >>= 1) {
        if (t < off) red[t] += red[t + off];
        __syncthreads();
    }
    if (t == 0) {
        float ppr = fmaxf(ctx_ppr[i], 1e-8f);
        col_bias[i]  = (alpha[0] * logf(ppr) + (red[0] + bd2[0])) * LOG2E;
        gate_full[i] = 1.0f / (1.0f + __expf(-(tscale[0] * ctx_trust[i])));
    }
}

// ---------------------------------------------------------------- fused fp32 -> fp16 convert
// x: 1048576 float4 | W_in: 786432 | W_out: 262144. Block 0 also inits gate/col_bias tails.
__global__ __launch_bounds__(256)
void cvt_all(const float* __restrict__ x, const float* __restrict__ wi,
             const float* __restrict__ wo,
             ushort* __restrict__ xf, ushort* __restrict__ wif, ushort* __restrict__ wof,
             float* __restrict__ gate_full, float* __restrict__ col_bias)
{
    if (blockIdx.x == 0) {
        #pragma unroll
        for (int j = threadIdx.x; j < NTOK - NCTX; j += 256) {
            gate_full[NCTX + j] = 1.0f;
            col_bias[NCTX + j]  = 0.0f;
        }
    }
    for (int i = blockIdx.x * 256 + threadIdx.x; i < 2097152; i += gridDim.x * 256) {
        const float* src; ushort* dst; int j;
        if (i < 1048576)      { src = x;  dst = xf;  j = i; }
        else if (i < 1835008) { src = wi; dst = wif; j = i - 1048576; }
        else                  { src = wo; dst = wof; j = i - 1835008; }
        float4 v = ((const float4*)src)[j];
        us4 h;
        h[0] = f2h(v.x); h[1] = f2h(v.y); h[2] = f2h(v.z); h[3] = f2h(v.w);
        ((us4*)dst)[j] = h;
    }
}

// ---------------------------------------------------------------- fp16 MFMA GEMM
// C = A @ B^T + bias. A [M][K] fp16, B [N][K] fp16, fp32 accum. BM=MT*32, BN=128, BK=32.
// EPI=1: scatter q/k fp16 [bh][tok][64] + V^T fp16 [bh][64][tok] gated (QKV).
// EPI=0: C[m*N+n] = acc + bias[n], fp32 out (out-proj).
template<int MT, int EPI>
__global__ __launch_bounds__(256, 3)
void gemm_f16(const ushort* __restrict__ Af, const ushort* __restrict__ Bf,
              const float* __restrict__ bias, float* __restrict__ C,
              ushort* __restrict__ qf, ushort* __restrict__ kf,
              ushort* __restrict__ vtf,
              const float* __restrict__ gate_full, int M, int N, int K)
{
    constexpr int BM = MT * 32;
    __shared__ ushort AS[BM * 32], BS[4096];

    const int t = threadIdx.x, lane = t & 63, wid = t >> 6;
    const int l15 = lane & 15, l4 = lane >> 4;
    const int wr = wid >> 1, wc = wid & 1;

    const int nwg = gridDim.x * gridDim.y;
    const int lin = blockIdx.y * gridDim.x + blockIdx.x;
    const int w   = (lin & 7) * (nwg >> 3) + (lin >> 3);
    const int bx  = w % gridDim.x, by = w / gridDim.x;
    const int m0 = by * BM, n0 = bx * 128;

    f4v acc[MT][4];
    #pragma unroll
    for (int mi = 0; mi < MT; mi++)
        #pragma unroll
        for (int nj = 0; nj < 4; nj++)
            #pragma unroll
            for (int r = 0; r < 4; r++) acc[mi][nj][r] = 0.0f;

    const int srow_l = lane >> 2;
    const int schunk = (lane & 3) ^ ((lane >> 2) & 3) ^ ((lane >> 4) & 3);
    const int rch = l4 ^ (l15 & 3) ^ ((l15 >> 2) & 3);

    for (int k0 = 0; k0 < K; k0 += 32) {
        __syncthreads();
        if (wid < 2) {
            #pragma unroll
            for (int i = 0; i < MT; i++) {      // wave stages MT*16 A-rows
                const int row = (wid & 1) * (MT * 16) + i * 16 + srow_l;
                GLDS16(Af + (size_t)(m0 + row) * K + k0 + schunk * 8,
                       AS + ((wid & 1) * MT + i) * 512);
            }
        } else {
            #pragma unroll
            for (int i = 0; i < 4; i++) {       // wave stages 64 B-rows
                const int row = (wid & 1) * 64 + i * 16 + srow_l;
                GLDS16(Bf + (size_t)(n0 + row) * K + k0 + schunk * 8,
                       BS + ((wid & 1) * 4 + i) * 512);
            }
        }
        __syncthreads();

        h8v af[MT], bf[4];
        #pragma unroll
        for (int mi = 0; mi < MT; mi++) {
            const int row = wr * (MT * 16) + mi * 16 + l15;
            af[mi] = *(const h8v*)&AS[row * 32 + rch * 8];
        }
        #pragma unroll
        for (int nj = 0; nj < 4; nj++) {
            const int row = wc * 64 + nj * 16 + l15;
            bf[nj] = *(const h8v*)&BS[row * 32 + rch * 8];
        }
        #pragma unroll
        for (int mi = 0; mi < MT; mi++)
            #pragma unroll
            for (int nj = 0; nj < 4; nj++)
                acc[mi][nj] = __builtin_amdgcn_mfma_f32_16x16x32_f16(af[mi], bf[nj], acc[mi][nj], 0, 0, 0);
    }

    if (EPI == 0) {
        #pragma unroll
        for (int mi = 0; mi < MT; mi++) {
            #pragma unroll
            for (int nj = 0; nj < 4; nj++) {
                const int n = n0 + wc * 64 + nj * 16 + l15;
                const float bn = bias[n];
                #pragma unroll
                for (int r = 0; r < 4; r++) {
                    const int m = m0 + wr * (MT * 16) + mi * 16 + l4 * 4 + r;
                    C[(size_t)m * N + n] = acc[mi][nj][r] + bn;
                }
            }
        }
    } else {
        const int sec = n0 >> 10;               // 0=q 1=k 2=v (uniform per block)
        #pragma unroll
        for (int mi = 0; mi < MT; mi++) {
            const int mbase = m0 + wr * (MT * 16) + mi * 16 + l4 * 4;
            const int bb = mbase >> 11, tok0 = mbase & 2047;
            #pragma unroll
            for (int nj = 0; nj < 4; nj++) {
                const int n = n0 + wc * 64 + nj * 16 + l15;
                const float bn = bias[n];
                const int rem = n & 1023, h = rem >> 6, jd = rem & 63;
                if (sec == 2) {
                    us4 hv;
                    #pragma unroll
                    for (int r = 0; r < 4; r++)
                        hv[r] = f2h((acc[mi][nj][r] + bn) * gate_full[tok0 + r]);
                    const size_t vb = ((size_t)((bb << 4) + h) * 64 + jd) * NTOK + tok0;
                    *(us4*)&vtf[vb] = hv;
                } else {
                    ushort* dst = sec ? kf : qf;
                    #pragma unroll
                    for (int r = 0; r < 4; r++) {
                        const size_t idx = ((size_t)((bb << 4) + h) * NTOK + (tok0 + r)) * 64 + jd;
                        dst[idx] = f2h(acc[mi][nj][r] + bn);
                    }
                }
            }
        }
    }
}

// ---------------------------------------------------------------- fp16 swapped-QK flash attention
// QBLK=64, 1024 blocks. exp2-domain softmax (col_bias pre-scaled); l computed on the MFMA
// pipe via ones-B-fragment (lsum layout == oacc layout -> shfl-free epilogue).
__global__ __launch_bounds__(256, 4)
void attn_f16(const ushort* __restrict__ qfp, const ushort* __restrict__ kfp,
              const ushort* __restrict__ vtf, const float* __restrict__ col_bias,
              ushort* __restrict__ attf)
{
    __shared__ ushort KS[2][4096];   // [buf][key 64][d 64] chunk-swizzled
    __shared__ ushort VS[2][4096];   // [buf][dh 64][kappa 64] pi-perm + swizzled
    __shared__ float  CBS[2][64];

    const int t = threadIdx.x, lane = t & 63, wid = t >> 6;
    const int lin = blockIdx.y * gridDim.x + blockIdx.x;   // 1024 blocks
    const int w   = (lin & 7) * 128 + (lin >> 3);          // bijective XCD swizzle
    const int bh  = w >> 5, qt = w & 31;

    const size_t qkbase = (size_t)bh * (NTOK * DHEAD);
    const size_t vtbase = (size_t)bh * (DHEAD * NTOK);
    const int l15 = lane & 15, l4 = lane >> 4;
    const int q0 = qt * 64 + wid * 16;

    h8v qf[2];
    #pragma unroll
    for (int s = 0; s < 2; s++)
        qf[s] = *(const h8v*)&qfp[qkbase + (size_t)(q0 + l15) * 64 + 32 * s + 8 * l4];

    h8v vone;
    #pragma unroll
    for (int i = 0; i < 8; i++) vone[i] = (_Float16)1.0f;

    f4v oacc[4], lsum;
    #pragma unroll
    for (int f = 0; f < 4; f++)
        #pragma unroll
        for (int r = 0; r < 4; r++) oacc[f][r] = 0.0f;
    #pragma unroll
    for (int r = 0; r < 4; r++) lsum[r] = 0.0f;
    float mreg = -INFINITY;   // exp2 domain

    us8 vreg[4];
    const int vj = lane & 7, vdh0 = lane >> 3;
    const int k0c  = 4 * (vj >> 2) + 2 * (vj & 1);
    const int off0 = ((vj >> 1) & 1) * 8;

    #define STAGE_K(nb, kt) do {                                                          \
        _Pragma("unroll")                                                                 \
        for (int i_ = 0; i_ < 4; i_++) {                                                  \
            const int row_ = wid * 32 + i_ * 8 + (lane >> 3);                             \
            const int sc_  = ((lane & 7) ^ (row_ & 7)) * 8;                               \
            GLDS16(kfp + qkbase + (size_t)((kt) + row_) * 64 + sc_,                       \
                   &KS[nb][0] + (wid * 4 + i_) * 512);                                    \
        }                                                                                 \
        if (wid == 0 && lane < 16) GLDS16(col_bias + (kt) + lane * 4, &CBS[nb][0]);       \
    } while (0)

    #define LOAD_V(kt) do {                                                               \
        _Pragma("unroll")                                                                 \
        for (int i_ = 0; i_ < 4; i_++) {                                                  \
            const int dh_ = (wid - 2) * 32 + 8 * i_ + vdh0;                               \
            vreg[i_] = *(const us8*)&vtf[vtbase + (size_t)dh_ * NTOK + (kt) + 8 * vj];    \
        }                                                                                 \
    } while (0)

    #define STORE_V(nb) do {                                                              \
        char* dp_ = (char*)&VS[nb][0];                                                    \
        _Pragma("unroll")                                                                 \
        for (int i_ = 0; i_ < 4; i_++) {                                                  \
            const int dh_ = (wid - 2) * 32 + 8 * i_ + vdh0;                               \
            const int b0_ = dh_ * 128 + ((k0c ^ (dh_ & 7)) * 16) + off0;                  \
            const int b1_ = dh_ * 128 + (((k0c + 1) ^ (dh_ & 7)) * 16) + off0;            \
            us4 lo4_, hi4_;                                                               \
            lo4_[0] = vreg[i_][0]; lo4_[1] = vreg[i_][1];                                 \
            lo4_[2] = vreg[i_][2]; lo4_[3] = vreg[i_][3];                                 \
            hi4_[0] = vreg[i_][4]; hi4_[1] = vreg[i_][5];                                 \
            hi4_[2] = vreg[i_][6]; hi4_[3] = vreg[i_][7];                                 \
            *(us4*)(dp_ + b0_) = lo4_;                                                    \
            *(us4*)(dp_ + b1_) = hi4_;                                                    \
        }                                                                                 \
    } while (0)

    if (wid < 2) STAGE_K(0, 0); else { LOAD_V(0); STORE_V(0); }
    __syncthreads();

    int cur = 0;
    for (int kt = 0; kt < 32; kt++) {
        const int nxt = cur ^ 1;
        if (kt < 31) { if (wid < 2) STAGE_K(nxt, (kt + 1) * 64); else LOAD_V((kt + 1) * 64); }

        // ---- QK^T: sa[g], row=key=16g+4l4+r, col=q=l15
        f4v sa[4];
        #pragma unroll
        for (int g = 0; g < 4; g++)
            #pragma unroll
            for (int r = 0; r < 4; r++) sa[g][r] = 0.0f;
        __builtin_amdgcn_s_setprio(1);
        #pragma unroll
        for (int s = 0; s < 2; s++) {
            #pragma unroll
            for (int g = 0; g < 4; g++) {
                const int row = 16 * g + l15;
                const int idx = row * 64 + (((4 * s + l4) ^ (l15 & 7))) * 8;
                h8v kfr = *(const h8v*)&KS[cur][idx];
                sa[g] = __builtin_amdgcn_mfma_f32_16x16x32_f16(kfr, qf[s], sa[g], 0, 0, 0);
            }
        }
        __builtin_amdgcn_s_setprio(0);

        // ---- logits in exp2 domain + defer-max (threshold 8*log2e -> p <= e^8, fp16-safe)
        const float SC2 = 0.125f * LOG2E;
        float sv[4][4], smax = -INFINITY;
        #pragma unroll
        for (int g = 0; g < 4; g++)
            #pragma unroll
            for (int r = 0; r < 4; r++) {
                const float x = sa[g][r] * SC2 + CBS[cur][16 * g + 4 * l4 + r];
                sv[g][r] = x;
                smax = fmaxf(smax, x);
            }
        if (__any(smax > mreg + 11.5415605f)) {
            float mx = smax;
            mx = fmaxf(mx, __shfl_xor(mx, 16));
            mx = fmaxf(mx, __shfl_xor(mx, 32));
            const float mnew = fmaxf(mreg, mx);
            const float fs = EXP2F(mreg - mnew);   // first tile: exp2(-inf)=0
            mreg = mnew;
            float fq[4];
            #pragma unroll
            for (int r = 0; r < 4; r++) fq[r] = __shfl(fs, 4 * l4 + r);
            #pragma unroll
            for (int r = 0; r < 4; r++) lsum[r] *= fq[r];
            #pragma unroll
            for (int f = 0; f < 4; f++)
                #pragma unroll
                for (int r = 0; r < 4; r++) oacc[f][r] *= fq[r];
        }

        // ---- p = exp2(x - m), pack to fp16 PV A-frags via pi (pure registers)
        union H8 { h8v v; __half2 h2[4]; };
        H8 pa[2];
        {
            float pv[4][4];
            #pragma unroll
            for (int g = 0; g < 4; g++)
                #pragma unroll
                for (int r = 0; r < 4; r++)
                    pv[g][r] = EXP2F(sv[g][r] - mreg);   // <= e^8, fits fp16
            #pragma unroll
            for (int s = 0; s < 2; s++)
                #pragma unroll
                for (int a = 0; a < 2; a++) {
                    const int g = 2 * s + a;
                    pa[s].h2[2 * a]     = __float22half2_rn(make_float2(pv[g][0], pv[g][1]));
                    pa[s].h2[2 * a + 1] = __float22half2_rn(make_float2(pv[g][2], pv[g][3]));
                }
        }

        // ---- PV: O[q][dh] += P x V; lsum += P x ones (rowsum on the MFMA pipe)
        __builtin_amdgcn_s_setprio(1);
        #pragma unroll
        for (int s = 0; s < 2; s++) {
            lsum = __builtin_amdgcn_mfma_f32_16x16x32_f16(pa[s].v, vone, lsum, 0, 0, 0);
            #pragma unroll
            for (int f = 0; f < 4; f++) {
                const int row = 16 * f + l15;
                const int idx = row * 64 + (((4 * s + l4) ^ (l15 & 7))) * 8;
                h8v vfr = *(const h8v*)&VS[cur][idx];
                oacc[f] = __builtin_amdgcn_mfma_f32_16x16x32_f16(pa[s].v, vfr, oacc[f], 0, 0, 0);
            }
        }
        __builtin_amdgcn_s_setprio(0);

        if (kt < 31 && wid >= 2) STORE_V(nxt);
        __syncthreads();
        cur = nxt;
    }

    // ---- epilogue: lsum layout == oacc layout (row=4l4+r) -> no cross-lane ops
    const int b = bh >> 4, h = bh & 15;
    #pragma unroll
    for (int r = 0; r < 4; r++) {
        const float inv = 1.0f / lsum[r];
        const int q = q0 + 4 * l4 + r;
        const size_t o = ((size_t)(b * NTOK + q)) * DMODEL + h * DHEAD + l15;
        #pragma unroll
        for (int f = 0; f < 4; f++)
            attf[o + 16 * f] = f2h(oacc[f][r] * inv);
    }
    #undef STAGE_K
    #undef LOAD_V
    #undef STORE_V
}

// ---------------------------------------------------------------- launch
extern "C" void kernel_launch(void* const* d_in, const int* in_sizes, int n_in,
                              void* d_out, int out_size, void* d_ws, size_t ws_size,
                              hipStream_t stream)
{
    const float* x         = (const float*)d_in[0];
    const float* ctx_ppr   = (const float*)d_in[2];
    const float* ctx_delta = (const float*)d_in[3];
    const float* ctx_trust = (const float*)d_in[4];
    const float* W_in      = (const float*)d_in[5];
    const float* b_in      = (const float*)d_in[6];
    const float* W_out     = (const float*)d_in[7];
    const float* b_out     = (const float*)d_in[8];
    const float* alpha     = (const float*)d_in[9];
    const float* tscale    = (const float*)d_in[10];
    const float* Wd1       = (const float*)d_in[11];
    const float* bd1       = (const float*)d_in[12];
    const float* Wd2       = (const float*)d_in[13];
    const float* bd2       = (const float*)d_in[14];
    float* out = (float*)d_out;

    float* ws = (float*)d_ws;
    float* gate_full = ws;                          // 2048 f
    float* col_bias  = ws + 2048;                   // 2048 f (exp2-domain)
    ushort* u = (ushort*)(ws + 4096);
    ushort* xf   = u;  u += 4194304;
    ushort* wif  = u;  u += 3145728;
    ushort* wof  = u;  u += 1048576;
    ushort* qf   = u;  u += 4194304;
    ushort* kf   = u;  u += 4194304;
    ushort* vtf  = u;  u += 4194304;
    ushort* attf = u;  u += 4194304;                // total ~48 MB

    bias_kernel<<<NCTX, 256, 0, stream>>>(ctx_ppr, ctx_delta, ctx_trust, alpha, tscale,
                                          Wd1, bd1, Wd2, bd2, gate_full, col_bias);
    cvt_all<<<2048, 256, 0, stream>>>(x, W_in, W_out, xf, wif, wof, gate_full, col_bias);

    gemm_f16<4, 1><<<dim3(24, 32), 256, 0, stream>>>(xf, wif, b_in, nullptr,
                                                     qf, kf, vtf, gate_full,
                                                     BTOT, 3 * DMODEL, DMODEL);
    attn_f16<<<dim3(32, 32), 256, 0, stream>>>(qf, kf, vtf, col_bias, attf);
    gemm_f16<1, 0><<<dim3(8, 128), 256, 0, stream>>>(attf, wof, b_out, out,
                                                     nullptr, nullptr, nullptr, nullptr,
                                                     BTOT, DMODEL, DMODEL);
}